// Round 1
// baseline (6358.258 us; speedup 1.0000x reference)
//
#include <hip/hip_runtime.h>

// One thread = one sample. Per (lq, var): recompute the position-local tree:
//   input cols -> td -> (pc0,pc1) -> db -> d0 -> dr1 -> dr2 -> tq -> t{0,1}
//   -> qb -> q0 -> qr1 -> qr2 -> silu -> qavg ; then head per lq.
// All weight reads are wave-uniform (scalar loads); activations live in VGPRs.

__device__ __forceinline__ float silu_f(float x) {
    return x * __builtin_amdgcn_rcpf(1.0f + __expf(-x));
}

#define D_BLOCK(LD, TT)                                                        \
  {                                                                            \
    const float e1 = s_eta * r1[2*(LD)],   e2 = s_phi * w2[2*(LD)];            \
    const float f1 = s_eta * r1[2*(LD)+1], f2 = s_phi * w2[2*(LD)+1];          \
    const float g0 = r0[2*(LD)],   g3 = r3[2*(LD)];                            \
    const float h0 = r0[2*(LD)+1], h3 = r3[2*(LD)+1];                          \
    float pc0[32], pc1[32];                                                    \
    _Pragma("unroll")                                                          \
    for (int c = 0; c < 32; c++) {                                             \
      float b = btd[c];                                                        \
      pc0[c] = fmaf(Wtd[4*c], g0, fmaf(Wtd[4*c+1], e1,                         \
               fmaf(Wtd[4*c+2], e2, fmaf(Wtd[4*c+3], g3, b))));                \
      pc1[c] = fmaf(Wtd[4*c], h0, fmaf(Wtd[4*c+1], f1,                         \
               fmaf(Wtd[4*c+2], f2, fmaf(Wtd[4*c+3], h3, b))));                \
    }                                                                          \
    float d0[32], sd[32];                                                      \
    _Pragma("unroll")                                                          \
    for (int c = 0; c < 30; c++) {                                             \
      float a = bdb[c];                                                        \
      _Pragma("unroll")                                                        \
      for (int i = 0; i < 32; i++) {                                           \
        a = fmaf(Wdb[64*c+2*i],   pc0[i], a);                                  \
        a = fmaf(Wdb[64*c+2*i+1], pc1[i], a);                                  \
      }                                                                        \
      d0[c] = a;                                                               \
    }                                                                          \
    d0[30] = da0[(LD)]; d0[31] = da1[(LD)];                                    \
    _Pragma("unroll")                                                          \
    for (int c = 0; c < 32; c++) sd[c] = silu_f(d0[c]);                        \
    float d1[32];                                                              \
    _Pragma("unroll")                                                          \
    for (int c = 0; c < 32; c++) {                                             \
      float a = bdr1[c] + d0[c];                                               \
      _Pragma("unroll")                                                        \
      for (int i = 0; i < 32; i++) {                                           \
        a = fmaf(Wdr1[96*c+3*i],   pc0[i], a);                                 \
        a = fmaf(Wdr1[96*c+3*i+1], pc1[i], a);                                 \
        a = fmaf(Wdr1[96*c+3*i+2], sd[i],  a);                                 \
      }                                                                        \
      d1[c] = a;                                                               \
    }                                                                          \
    _Pragma("unroll")                                                          \
    for (int c = 0; c < 32; c++) sd[c] = silu_f(d1[c]);                        \
    _Pragma("unroll")                                                          \
    for (int c = 0; c < 32; c++) {                                             \
      float a = bdr2[c] + d0[c];                                               \
      _Pragma("unroll")                                                        \
      for (int i = 0; i < 32; i++) {                                           \
        a = fmaf(Wdr2[96*c+3*i],   pc0[i], a);                                 \
        a = fmaf(Wdr2[96*c+3*i+1], pc1[i], a);                                 \
        a = fmaf(Wdr2[96*c+3*i+2], sd[i],  a);                                 \
      }                                                                        \
      d1[c] = a;                                                               \
    }                                                                          \
    _Pragma("unroll")                                                          \
    for (int c = 0; c < 32; c++) sd[c] = silu_f(d1[c]);                        \
    _Pragma("unroll")                                                          \
    for (int c = 0; c < 32; c++) {                                             \
      float a = btq[c];                                                        \
      _Pragma("unroll")                                                        \
      for (int i = 0; i < 32; i++) a = fmaf(Wtq[32*c+i], sd[i], a);            \
      TT[c] = a;                                                               \
    }                                                                          \
  }

__global__ __launch_bounds__(64, 1) void resnet_all(
    const float* __restrict__ P,    // [N,4,12]
    const float* __restrict__ DA,   // [N,12]
    const float* __restrict__ QA,   // [N,6]
    const float* __restrict__ VA,   // [N,2]
    const float* __restrict__ Wtd,  const float* __restrict__ btd,
    const float* __restrict__ Wdb,  const float* __restrict__ bdb,
    const float* __restrict__ Wdr1, const float* __restrict__ bdr1,
    const float* __restrict__ Wdr2, const float* __restrict__ bdr2,
    const float* __restrict__ Wtq,  const float* __restrict__ btq,
    const float* __restrict__ Wqb,  const float* __restrict__ bqb,
    const float* __restrict__ Wqr1, const float* __restrict__ bqr1,
    const float* __restrict__ Wqr2, const float* __restrict__ bqr2,
    const float* __restrict__ Wtv,  const float* __restrict__ btv,
    const float* __restrict__ Wv1,  const float* __restrict__ bv1,
    const float* __restrict__ Wv2,  const float* __restrict__ bv2,
    const float* __restrict__ Wvs,  const float* __restrict__ bvs,
    float* __restrict__ out, int n_total)
{
    const int n = blockIdx.x * 64 + threadIdx.x;
    if (n >= n_total) return;
    const float* pn = P + n * 48;
    const float va0 = VA[n*2+0], va1 = VA[n*2+1];

    float out_acc = bvs[0];

    #pragma unroll 1
    for (int lq = 0; lq < 3; ++lq) {
        // hoist the 4 input positions (4*lq .. 4*lq+3), pre-wrap phi row
        float r0[4], r1[4], w2[4], r3[4];
        #pragma unroll
        for (int j = 0; j < 4; j++) {
            const int t = 4*lq + j;
            r0[j] = pn[t];
            r1[j] = pn[12 + t];
            float y = pn[24 + t] + 1.0f;
            y = y - 2.0f * floorf(y * 0.5f);
            w2[j] = y - 1.0f;
            r3[j] = pn[36 + t];
        }
        const float qa30 = QA[n*6 + lq];
        const float qa31 = QA[n*6 + 3 + lq];
        float da0[2], da1[2];
        #pragma unroll
        for (int ld = 0; ld < 2; ld++) {
            da0[ld] = DA[n*12 + (2*lq + ld)];
            da1[ld] = DA[n*12 + 6 + (2*lq + ld)];
        }

        float qavg[32];
        #pragma unroll
        for (int c = 0; c < 32; c++) qavg[c] = 0.0f;

        #pragma unroll 1
        for (int var = 0; var < 4; ++var) {
            const float s_eta = (var >= 2) ? -1.0f : 1.0f;
            const float s_phi = (var == 1 || var == 2) ? -1.0f : 1.0f;
            float t0[32], t1[32];
            D_BLOCK(0, t0)
            D_BLOCK(1, t1)
            // q part
            float q0[32];
            #pragma unroll
            for (int c = 0; c < 30; c++) {
                float a = bqb[c];
                #pragma unroll
                for (int i = 0; i < 32; i++) {
                    a = fmaf(Wqb[64*c+2*i],   t0[i], a);
                    a = fmaf(Wqb[64*c+2*i+1], t1[i], a);
                }
                q0[c] = a;
            }
            q0[30] = qa30; q0[31] = qa31;
            float sq[32];
            #pragma unroll
            for (int c = 0; c < 32; c++) sq[c] = silu_f(q0[c]);
            float q1[32];
            #pragma unroll
            for (int c = 0; c < 32; c++) {
                float a = bqr1[c] + q0[c];
                #pragma unroll
                for (int i = 0; i < 32; i++) {
                    a = fmaf(Wqr1[96*c+3*i],   t0[i], a);
                    a = fmaf(Wqr1[96*c+3*i+1], t1[i], a);
                    a = fmaf(Wqr1[96*c+3*i+2], sq[i], a);
                }
                q1[c] = a;
            }
            #pragma unroll
            for (int c = 0; c < 32; c++) sq[c] = silu_f(q1[c]);
            #pragma unroll
            for (int c = 0; c < 32; c++) {
                float a = bqr2[c] + q0[c];
                #pragma unroll
                for (int i = 0; i < 32; i++) {
                    a = fmaf(Wqr2[96*c+3*i],   t0[i], a);
                    a = fmaf(Wqr2[96*c+3*i+1], t1[i], a);
                    a = fmaf(Wqr2[96*c+3*i+2], sq[i], a);
                }
                qavg[c] += silu_f(a);
            }
        } // var

        #pragma unroll
        for (int c = 0; c < 32; c++) qavg[c] *= 0.25f;

        // head for this lq (tv / v1 / v2 are 1x1; vs folds into out_acc)
        float u0[64];
        #pragma unroll
        for (int c = 0; c < 64; c++) {
            float a = fmaf(Wtv[34*c+32], va0, fmaf(Wtv[34*c+33], va1, btv[c]));
            #pragma unroll
            for (int i = 0; i < 32; i++) a = fmaf(Wtv[34*c+i], qavg[i], a);
            u0[c] = a;
        }
        float su[64];
        #pragma unroll
        for (int c = 0; c < 64; c++) su[c] = silu_f(u0[c]);
        float u1[64];
        #pragma unroll
        for (int c = 0; c < 64; c++) {
            float a = bv1[c] + u0[c];
            #pragma unroll
            for (int i = 0; i < 64; i++) a = fmaf(Wv1[64*c+i], su[i], a);
            u1[c] = a;
        }
        #pragma unroll
        for (int c = 0; c < 64; c++) su[c] = silu_f(u1[c]);
        #pragma unroll
        for (int c = 0; c < 64; c++) {
            float a = bv2[c] + u0[c];
            #pragma unroll
            for (int i = 0; i < 64; i++) a = fmaf(Wv2[64*c+i], su[i], a);
            out_acc = fmaf(Wvs[3*c + lq], silu_f(a), out_acc);
        }
    } // lq

    out[n] = out_acc;
}

extern "C" void kernel_launch(void* const* d_in, const int* in_sizes, int n_in,
                              void* d_out, int out_size, void* d_ws, size_t ws_size,
                              hipStream_t stream)
{
    (void)n_in; (void)d_ws; (void)ws_size; (void)out_size;
    // d_in[0] = x (UNUSED by the reference)
    const float* P   = (const float*)d_in[1];
    const float* DA  = (const float*)d_in[2];
    const float* QA  = (const float*)d_in[3];
    const float* VA  = (const float*)d_in[4];
    const float* Wtd = (const float*)d_in[5];   const float* btd = (const float*)d_in[6];
    const float* Wdb = (const float*)d_in[7];   const float* bdb = (const float*)d_in[8];
    const float* Wdr1= (const float*)d_in[9];   const float* bdr1= (const float*)d_in[10];
    const float* Wdr2= (const float*)d_in[11];  const float* bdr2= (const float*)d_in[12];
    const float* Wtq = (const float*)d_in[13];  const float* btq = (const float*)d_in[14];
    const float* Wqb = (const float*)d_in[15];  const float* bqb = (const float*)d_in[16];
    const float* Wqr1= (const float*)d_in[17];  const float* bqr1= (const float*)d_in[18];
    const float* Wqr2= (const float*)d_in[19];  const float* bqr2= (const float*)d_in[20];
    const float* Wtv = (const float*)d_in[21];  const float* btv = (const float*)d_in[22];
    const float* Wv1 = (const float*)d_in[23];  const float* bv1 = (const float*)d_in[24];
    const float* Wv2 = (const float*)d_in[25];  const float* bv2 = (const float*)d_in[26];
    const float* Wvs = (const float*)d_in[27];  const float* bvs = (const float*)d_in[28];
    float* out = (float*)d_out;

    const int n_total = in_sizes[1] / 48;     // p is [N,4,12]
    const int grid = (n_total + 63) / 64;

    resnet_all<<<dim3(grid), dim3(64), 0, stream>>>(
        P, DA, QA, VA,
        Wtd, btd, Wdb, bdb, Wdr1, bdr1, Wdr2, bdr2,
        Wtq, btq, Wqb, bqb, Wqr1, bqr1, Wqr2, bqr2,
        Wtv, btv, Wv1, bv1, Wv2, bv2, Wvs, bvs,
        out, n_total);
}

// Round 2
// 4603.329 us; speedup vs baseline: 1.3812x; 1.3812x over previous
//
#include <hip/hip_runtime.h>

// Composed-weight version. A tiny precompute kernel folds all linear-linear
// compositions (td->db, td->dr1p, td->dr2p, tq->qb, tq->qr1t, tq->qr2t) into
// d_ws, eliminating the pc0/pc1 and t0/t1 register arrays and ~45% of FLOPs.
// Main kernel: 1 thread = 1 sample, all weights wave-uniform scalar loads,
// activations in VGPRs, peak liveness ~230 floats -> fits 256 VGPR, 2 waves/EU.

#define OFF_A    0      // [30][8]
#define OFF_AB   240    // [30]
#define OFF_M1   270    // [32][8]
#define OFF_M1B  526    // [32]
#define OFF_M2   558    // [32][8]
#define OFF_M2B  814    // [32]
#define OFF_W1S  846    // [32][32]
#define OFF_W2S  1870   // [32][32]
#define OFF_Q    2894   // [30][64]
#define OFF_QB   4814   // [30]
#define OFF_N1   4844   // [32][64]
#define OFF_N1B  6892   // [32]
#define OFF_N2   6924   // [32][64]
#define OFF_N2B  8972   // [32]
#define OFF_U1S  9004   // [32][32]
#define OFF_U2S  10028  // [32][32]
#define WS_FLOATS 11052

__device__ __forceinline__ float silu_f(float x) {
    return x * __builtin_amdgcn_rcpf(1.0f + __expf(-x));
}

__global__ void precompute_ws(
    const float* __restrict__ Wtd, const float* __restrict__ btd,
    const float* __restrict__ Wdb, const float* __restrict__ bdb,
    const float* __restrict__ Wdr1, const float* __restrict__ bdr1,
    const float* __restrict__ Wdr2, const float* __restrict__ bdr2,
    const float* __restrict__ Wtq, const float* __restrict__ btq,
    const float* __restrict__ Wqb, const float* __restrict__ bqb,
    const float* __restrict__ Wqr1, const float* __restrict__ bqr1,
    const float* __restrict__ Wqr2, const float* __restrict__ bqr2,
    float* __restrict__ ws)
{
    const int t = threadIdx.x;  // 256 threads, 1 block
    // A[30][8] (db o td), AB[30]
    for (int c = t; c < 30; c += 256) {
        for (int j = 0; j < 4; ++j) {
            float a0 = 0.f, a1 = 0.f;
            for (int i = 0; i < 32; ++i) {
                a0 += Wdb[64*c + 2*i]     * Wtd[4*i + j];
                a1 += Wdb[64*c + 2*i + 1] * Wtd[4*i + j];
            }
            ws[OFF_A + 8*c + j]     = a0;
            ws[OFF_A + 8*c + 4 + j] = a1;
        }
        float b = bdb[c];
        for (int i = 0; i < 32; ++i)
            b += (Wdb[64*c + 2*i] + Wdb[64*c + 2*i + 1]) * btd[i];
        ws[OFF_AB + c] = b;
    }
    // M1/M2 [32][8] (dr{1,2} p-part o td) + biases (folding bdr{1,2})
    for (int c = t; c < 32; c += 256) {
        for (int j = 0; j < 4; ++j) {
            float a0=0.f,a1=0.f,b0=0.f,b1=0.f;
            for (int i = 0; i < 32; ++i) {
                float w = Wtd[4*i + j];
                a0 += Wdr1[96*c + 3*i]     * w;
                a1 += Wdr1[96*c + 3*i + 1] * w;
                b0 += Wdr2[96*c + 3*i]     * w;
                b1 += Wdr2[96*c + 3*i + 1] * w;
            }
            ws[OFF_M1 + 8*c + j] = a0; ws[OFF_M1 + 8*c + 4 + j] = a1;
            ws[OFF_M2 + 8*c + j] = b0; ws[OFF_M2 + 8*c + 4 + j] = b1;
        }
        float b1s = bdr1[c], b2s = bdr2[c];
        for (int i = 0; i < 32; ++i) {
            b1s += (Wdr1[96*c + 3*i] + Wdr1[96*c + 3*i + 1]) * btd[i];
            b2s += (Wdr2[96*c + 3*i] + Wdr2[96*c + 3*i + 1]) * btd[i];
        }
        ws[OFF_M1B + c] = b1s; ws[OFF_M2B + c] = b2s;
    }
    // W1S/W2S: packed sd-columns of Wdr1/Wdr2
    for (int idx = t; idx < 1024; idx += 256) {
        int c = idx >> 5, i = idx & 31;
        ws[OFF_W1S + idx] = Wdr1[96*c + 3*i + 2];
        ws[OFF_W2S + idx] = Wdr2[96*c + 3*i + 2];
    }
    // Q [30][64] (qb o tq), QB[30]
    for (int idx = t; idx < 30*64; idx += 256) {
        int c = idx >> 6, k = idx & 63, z = k >> 5, kk = k & 31;
        float a = 0.f;
        for (int i = 0; i < 32; ++i) a += Wqb[64*c + 2*i + z] * Wtq[32*i + kk];
        ws[OFF_Q + idx] = a;
    }
    for (int c = t; c < 30; c += 256) {
        float b = bqb[c];
        for (int i = 0; i < 32; ++i)
            b += (Wqb[64*c + 2*i] + Wqb[64*c + 2*i + 1]) * btq[i];
        ws[OFF_QB + c] = b;
    }
    // N1/N2 [32][64] (qr{1,2} t-part o tq) + biases (folding bqr{1,2})
    for (int idx = t; idx < 32*64; idx += 256) {
        int c = idx >> 6, k = idx & 63, z = k >> 5, kk = k & 31;
        float a1 = 0.f, a2 = 0.f;
        for (int i = 0; i < 32; ++i) {
            float w = Wtq[32*i + kk];
            a1 += Wqr1[96*c + 3*i + z] * w;
            a2 += Wqr2[96*c + 3*i + z] * w;
        }
        ws[OFF_N1 + idx] = a1; ws[OFF_N2 + idx] = a2;
    }
    for (int c = t; c < 32; c += 256) {
        float b1s = bqr1[c], b2s = bqr2[c];
        for (int i = 0; i < 32; ++i) {
            b1s += (Wqr1[96*c + 3*i] + Wqr1[96*c + 3*i + 1]) * btq[i];
            b2s += (Wqr2[96*c + 3*i] + Wqr2[96*c + 3*i + 1]) * btq[i];
        }
        ws[OFF_N1B + c] = b1s; ws[OFF_N2B + c] = b2s;
        for (int i = 0; i < 32; ++i) {
            ws[OFF_U1S + 32*c + i] = Wqr1[96*c + 3*i + 2];
            ws[OFF_U2S + 32*c + i] = Wqr2[96*c + 3*i + 2];
        }
    }
}

#define D_PART(LD, SDL)                                                        \
  {                                                                            \
    const int p0 = 4*lq + 2*(LD);                                              \
    float xi[8];                                                               \
    _Pragma("unroll") for (int h = 0; h < 2; ++h) {                            \
      const int pp = p0 + h;                                                   \
      xi[4*h+0] = pn[pp];                                                      \
      xi[4*h+1] = s_eta * pn[12+pp];                                           \
      float y = pn[24+pp] + 1.f; y = y - 2.f*floorf(y*0.5f);                   \
      xi[4*h+2] = s_phi * (y - 1.f);                                           \
      xi[4*h+3] = pn[36+pp];                                                   \
    }                                                                          \
    float d0[32];                                                              \
    _Pragma("unroll") for (int c = 0; c < 30; ++c) {                           \
      float a = ws[OFF_AB + c];                                                \
      _Pragma("unroll") for (int j = 0; j < 8; ++j)                            \
        a = fmaf(ws[OFF_A + 8*c + j], xi[j], a);                               \
      d0[c] = a;                                                               \
    }                                                                          \
    d0[30] = DA[n*12 + (2*lq + (LD))];                                         \
    d0[31] = DA[n*12 + 6 + (2*lq + (LD))];                                     \
    float m1[32], m2[32];                                                      \
    _Pragma("unroll") for (int c = 0; c < 32; ++c) {                           \
      float a = ws[OFF_M1B + c];                                               \
      _Pragma("unroll") for (int j = 0; j < 8; ++j)                            \
        a = fmaf(ws[OFF_M1 + 8*c + j], xi[j], a);                              \
      m1[c] = a;                                                               \
    }                                                                          \
    _Pragma("unroll") for (int c = 0; c < 32; ++c) {                           \
      float a = ws[OFF_M2B + c];                                               \
      _Pragma("unroll") for (int j = 0; j < 8; ++j)                            \
        a = fmaf(ws[OFF_M2 + 8*c + j], xi[j], a);                              \
      m2[c] = a;                                                               \
    }                                                                          \
    float sd[32];                                                              \
    _Pragma("unroll") for (int c = 0; c < 32; ++c) sd[c] = silu_f(d0[c]);      \
    _Pragma("unroll") for (int c = 0; c < 32; ++c) {                           \
      float a = m1[c] + d0[c];                                                 \
      _Pragma("unroll") for (int i = 0; i < 32; ++i)                           \
        a = fmaf(ws[OFF_W1S + 32*c + i], sd[i], a);                            \
      m1[c] = a;                                                               \
    }                                                                          \
    _Pragma("unroll") for (int c = 0; c < 32; ++c) sd[c] = silu_f(m1[c]);      \
    _Pragma("unroll") for (int c = 0; c < 32; ++c) {                           \
      float a = m2[c] + d0[c];                                                 \
      _Pragma("unroll") for (int i = 0; i < 32; ++i)                           \
        a = fmaf(ws[OFF_W2S + 32*c + i], sd[i], a);                            \
      SDL[c] = silu_f(a);                                                      \
    }                                                                          \
  }

__global__ __launch_bounds__(64, 2) void resnet_main(
    const float* __restrict__ P,  const float* __restrict__ DA,
    const float* __restrict__ QA, const float* __restrict__ VA,
    const float* __restrict__ ws,
    const float* __restrict__ Wtv, const float* __restrict__ btv,
    const float* __restrict__ Wv1, const float* __restrict__ bv1,
    const float* __restrict__ Wv2, const float* __restrict__ bv2,
    const float* __restrict__ Wvs, const float* __restrict__ bvs,
    float* __restrict__ out, int n_total)
{
    const int n = blockIdx.x * 64 + threadIdx.x;
    if (n >= n_total) return;
    const float* pn = P + n * 48;

    float out_acc = bvs[0];

    #pragma unroll 1
    for (int lq = 0; lq < 3; ++lq) {
        float qavg[32];
        #pragma unroll
        for (int c = 0; c < 32; ++c) qavg[c] = 0.f;

        #pragma unroll 1
        for (int var = 0; var < 4; ++var) {
            const float s_eta = (var >= 2) ? -1.f : 1.f;
            const float s_phi = (var == 1 || var == 2) ? -1.f : 1.f;

            float sdl0[32], sdl1[32];
            D_PART(0, sdl0)
            D_PART(1, sdl1)

            // q-part: composed q0/n1/n2 from sdl0|sdl1
            float q0[32];
            #pragma unroll
            for (int c = 0; c < 30; ++c) {
                float a = ws[OFF_QB + c];
                #pragma unroll
                for (int k = 0; k < 32; ++k) {
                    a = fmaf(ws[OFF_Q + 64*c + k],      sdl0[k], a);
                    a = fmaf(ws[OFF_Q + 64*c + 32 + k], sdl1[k], a);
                }
                q0[c] = a;
            }
            q0[30] = QA[n*6 + lq];
            q0[31] = QA[n*6 + 3 + lq];
            float n1[32], n2[32];
            #pragma unroll
            for (int c = 0; c < 32; ++c) {
                float a = ws[OFF_N1B + c];
                #pragma unroll
                for (int k = 0; k < 32; ++k) {
                    a = fmaf(ws[OFF_N1 + 64*c + k],      sdl0[k], a);
                    a = fmaf(ws[OFF_N1 + 64*c + 32 + k], sdl1[k], a);
                }
                n1[c] = a;
            }
            #pragma unroll
            for (int c = 0; c < 32; ++c) {
                float a = ws[OFF_N2B + c];
                #pragma unroll
                for (int k = 0; k < 32; ++k) {
                    a = fmaf(ws[OFF_N2 + 64*c + k],      sdl0[k], a);
                    a = fmaf(ws[OFF_N2 + 64*c + 32 + k], sdl1[k], a);
                }
                n2[c] = a;
            }
            // sdl0/sdl1 dead here
            float sq[32];
            #pragma unroll
            for (int c = 0; c < 32; ++c) sq[c] = silu_f(q0[c]);
            #pragma unroll
            for (int c = 0; c < 32; ++c) {
                float a = n1[c] + q0[c];
                #pragma unroll
                for (int i = 0; i < 32; ++i)
                    a = fmaf(ws[OFF_U1S + 32*c + i], sq[i], a);
                n1[c] = a;
            }
            #pragma unroll
            for (int c = 0; c < 32; ++c) sq[c] = silu_f(n1[c]);
            #pragma unroll
            for (int c = 0; c < 32; ++c) {
                float a = n2[c] + q0[c];
                #pragma unroll
                for (int i = 0; i < 32; ++i)
                    a = fmaf(ws[OFF_U2S + 32*c + i], sq[i], a);
                qavg[c] += silu_f(a);
            }
        } // var

        #pragma unroll
        for (int c = 0; c < 32; ++c) qavg[c] *= 0.25f;

        // head (tv/v1/v2/vs folded)
        const float va0 = VA[n*2], va1 = VA[n*2+1];
        float u0[64];
        #pragma unroll
        for (int c = 0; c < 64; ++c) {
            float a = fmaf(Wtv[34*c+32], va0, fmaf(Wtv[34*c+33], va1, btv[c]));
            #pragma unroll
            for (int i = 0; i < 32; ++i) a = fmaf(Wtv[34*c+i], qavg[i], a);
            u0[c] = a;
        }
        float su[64];
        #pragma unroll
        for (int c = 0; c < 64; ++c) su[c] = silu_f(u0[c]);
        float su2[64];
        #pragma unroll
        for (int c = 0; c < 64; ++c) {
            float a = bv1[c] + u0[c];
            #pragma unroll
            for (int i = 0; i < 64; ++i) a = fmaf(Wv1[64*c+i], su[i], a);
            su2[c] = silu_f(a);
        }
        #pragma unroll
        for (int c = 0; c < 64; ++c) {
            float a = bv2[c] + u0[c];
            #pragma unroll
            for (int i = 0; i < 64; ++i) a = fmaf(Wv2[64*c+i], su2[i], a);
            out_acc = fmaf(Wvs[3*c + lq], silu_f(a), out_acc);
        }
    } // lq

    out[n] = out_acc;
}

extern "C" void kernel_launch(void* const* d_in, const int* in_sizes, int n_in,
                              void* d_out, int out_size, void* d_ws, size_t ws_size,
                              hipStream_t stream)
{
    (void)n_in; (void)ws_size; (void)out_size;
    const float* P   = (const float*)d_in[1];
    const float* DA  = (const float*)d_in[2];
    const float* QA  = (const float*)d_in[3];
    const float* VA  = (const float*)d_in[4];
    const float* Wtd = (const float*)d_in[5];   const float* btd = (const float*)d_in[6];
    const float* Wdb = (const float*)d_in[7];   const float* bdb = (const float*)d_in[8];
    const float* Wdr1= (const float*)d_in[9];   const float* bdr1= (const float*)d_in[10];
    const float* Wdr2= (const float*)d_in[11];  const float* bdr2= (const float*)d_in[12];
    const float* Wtq = (const float*)d_in[13];  const float* btq = (const float*)d_in[14];
    const float* Wqb = (const float*)d_in[15];  const float* bqb = (const float*)d_in[16];
    const float* Wqr1= (const float*)d_in[17];  const float* bqr1= (const float*)d_in[18];
    const float* Wqr2= (const float*)d_in[19];  const float* bqr2= (const float*)d_in[20];
    const float* Wtv = (const float*)d_in[21];  const float* btv = (const float*)d_in[22];
    const float* Wv1 = (const float*)d_in[23];  const float* bv1 = (const float*)d_in[24];
    const float* Wv2 = (const float*)d_in[25];  const float* bv2 = (const float*)d_in[26];
    const float* Wvs = (const float*)d_in[27];  const float* bvs = (const float*)d_in[28];
    float* out = (float*)d_out;

    const int n_total = in_sizes[1] / 48;   // p is [N,4,12]

    precompute_ws<<<dim3(1), dim3(256), 0, stream>>>(
        Wtd, btd, Wdb, bdb, Wdr1, bdr1, Wdr2, bdr2,
        Wtq, btq, Wqb, bqb, Wqr1, bqr1, Wqr2, bqr2, (float*)d_ws);

    const int grid = (n_total + 63) / 64;
    resnet_main<<<dim3(grid), dim3(64), 0, stream>>>(
        P, DA, QA, VA, (const float*)d_ws,
        Wtv, btv, Wv1, bv1, Wv2, bv2, Wvs, bvs, out, n_total);
}

// Round 3
// 4275.965 us; speedup vs baseline: 1.4870x; 1.0766x over previous
//
#include <hip/hip_runtime.h>

// Composed-weight version, spill-free: launch_bounds(64,1) lets the allocator
// use up to 512 VGPRs (expected ~240-256, no scratch). Peak liveness ~200-230
// floats by construction:
//   D-part:  xi(8)+d0(32)+m1(32)+m2(32)+sd(32)+sdl0(32)+qavg(32) ~ 200
//   Q-part:  sdl0/1(64)+q0(32)+n1(32)+n2(32)+qavg(32)            ~ 192
//   head:    u0(64)+su(64)+su2(64)                                ~ 192
// All weights wave-uniform (scalar cache); activations stay in VGPRs.

#define OFF_A    0      // [30][8]
#define OFF_AB   240    // [30]
#define OFF_M1   270    // [32][8]
#define OFF_M1B  526    // [32]
#define OFF_M2   558    // [32][8]
#define OFF_M2B  814    // [32]
#define OFF_W1S  846    // [32][32]
#define OFF_W2S  1870   // [32][32]
#define OFF_Q    2894   // [30][64]
#define OFF_QB   4814   // [30]
#define OFF_N1   4844   // [32][64]
#define OFF_N1B  6892   // [32]
#define OFF_N2   6924   // [32][64]
#define OFF_N2B  8972   // [32]
#define OFF_U1S  9004   // [32][32]
#define OFF_U2S  10028  // [32][32]
#define WS_FLOATS 11052

__device__ __forceinline__ float silu_f(float x) {
    return x * __builtin_amdgcn_rcpf(1.0f + __expf(-x));
}

__global__ void precompute_ws(
    const float* __restrict__ Wtd, const float* __restrict__ btd,
    const float* __restrict__ Wdb, const float* __restrict__ bdb,
    const float* __restrict__ Wdr1, const float* __restrict__ bdr1,
    const float* __restrict__ Wdr2, const float* __restrict__ bdr2,
    const float* __restrict__ Wtq, const float* __restrict__ btq,
    const float* __restrict__ Wqb, const float* __restrict__ bqb,
    const float* __restrict__ Wqr1, const float* __restrict__ bqr1,
    const float* __restrict__ Wqr2, const float* __restrict__ bqr2,
    float* __restrict__ ws)
{
    const int t = threadIdx.x;  // 256 threads, 1 block
    for (int c = t; c < 30; c += 256) {
        for (int j = 0; j < 4; ++j) {
            float a0 = 0.f, a1 = 0.f;
            for (int i = 0; i < 32; ++i) {
                a0 += Wdb[64*c + 2*i]     * Wtd[4*i + j];
                a1 += Wdb[64*c + 2*i + 1] * Wtd[4*i + j];
            }
            ws[OFF_A + 8*c + j]     = a0;
            ws[OFF_A + 8*c + 4 + j] = a1;
        }
        float b = bdb[c];
        for (int i = 0; i < 32; ++i)
            b += (Wdb[64*c + 2*i] + Wdb[64*c + 2*i + 1]) * btd[i];
        ws[OFF_AB + c] = b;
    }
    for (int c = t; c < 32; c += 256) {
        for (int j = 0; j < 4; ++j) {
            float a0=0.f,a1=0.f,b0=0.f,b1=0.f;
            for (int i = 0; i < 32; ++i) {
                float w = Wtd[4*i + j];
                a0 += Wdr1[96*c + 3*i]     * w;
                a1 += Wdr1[96*c + 3*i + 1] * w;
                b0 += Wdr2[96*c + 3*i]     * w;
                b1 += Wdr2[96*c + 3*i + 1] * w;
            }
            ws[OFF_M1 + 8*c + j] = a0; ws[OFF_M1 + 8*c + 4 + j] = a1;
            ws[OFF_M2 + 8*c + j] = b0; ws[OFF_M2 + 8*c + 4 + j] = b1;
        }
        float b1s = bdr1[c], b2s = bdr2[c];
        for (int i = 0; i < 32; ++i) {
            b1s += (Wdr1[96*c + 3*i] + Wdr1[96*c + 3*i + 1]) * btd[i];
            b2s += (Wdr2[96*c + 3*i] + Wdr2[96*c + 3*i + 1]) * btd[i];
        }
        ws[OFF_M1B + c] = b1s; ws[OFF_M2B + c] = b2s;
    }
    for (int idx = t; idx < 1024; idx += 256) {
        int c = idx >> 5, i = idx & 31;
        ws[OFF_W1S + idx] = Wdr1[96*c + 3*i + 2];
        ws[OFF_W2S + idx] = Wdr2[96*c + 3*i + 2];
    }
    for (int idx = t; idx < 30*64; idx += 256) {
        int c = idx >> 6, k = idx & 63, z = k >> 5, kk = k & 31;
        float a = 0.f;
        for (int i = 0; i < 32; ++i) a += Wqb[64*c + 2*i + z] * Wtq[32*i + kk];
        ws[OFF_Q + idx] = a;
    }
    for (int c = t; c < 30; c += 256) {
        float b = bqb[c];
        for (int i = 0; i < 32; ++i)
            b += (Wqb[64*c + 2*i] + Wqb[64*c + 2*i + 1]) * btq[i];
        ws[OFF_QB + c] = b;
    }
    for (int idx = t; idx < 32*64; idx += 256) {
        int c = idx >> 6, k = idx & 63, z = k >> 5, kk = k & 31;
        float a1 = 0.f, a2 = 0.f;
        for (int i = 0; i < 32; ++i) {
            float w = Wtq[32*i + kk];
            a1 += Wqr1[96*c + 3*i + z] * w;
            a2 += Wqr2[96*c + 3*i + z] * w;
        }
        ws[OFF_N1 + idx] = a1; ws[OFF_N2 + idx] = a2;
    }
    for (int c = t; c < 32; c += 256) {
        float b1s = bqr1[c], b2s = bqr2[c];
        for (int i = 0; i < 32; ++i) {
            b1s += (Wqr1[96*c + 3*i] + Wqr1[96*c + 3*i + 1]) * btq[i];
            b2s += (Wqr2[96*c + 3*i] + Wqr2[96*c + 3*i + 1]) * btq[i];
        }
        ws[OFF_N1B + c] = b1s; ws[OFF_N2B + c] = b2s;
        for (int i = 0; i < 32; ++i) {
            ws[OFF_U1S + 32*c + i] = Wqr1[96*c + 3*i + 2];
            ws[OFF_U2S + 32*c + i] = Wqr2[96*c + 3*i + 2];
        }
    }
}

#define D_PART(LD, SDL)                                                        \
  {                                                                            \
    const int p0 = 4*lq + 2*(LD);                                              \
    float xi[8];                                                               \
    _Pragma("unroll") for (int h = 0; h < 2; ++h) {                            \
      const int pp = p0 + h;                                                   \
      xi[4*h+0] = pn[pp];                                                      \
      xi[4*h+1] = s_eta * pn[12+pp];                                           \
      float y = pn[24+pp] + 1.f; y = y - 2.f*floorf(y*0.5f);                   \
      xi[4*h+2] = s_phi * (y - 1.f);                                           \
      xi[4*h+3] = pn[36+pp];                                                   \
    }                                                                          \
    float d0[32];                                                              \
    _Pragma("unroll") for (int c = 0; c < 30; ++c) {                           \
      float a = ws[OFF_AB + c];                                                \
      _Pragma("unroll") for (int j = 0; j < 8; ++j)                            \
        a = fmaf(ws[OFF_A + 8*c + j], xi[j], a);                               \
      d0[c] = a;                                                               \
    }                                                                          \
    d0[30] = DA[n*12 + (2*lq + (LD))];                                         \
    d0[31] = DA[n*12 + 6 + (2*lq + (LD))];                                     \
    float m1[32], m2[32];                                                      \
    _Pragma("unroll") for (int c = 0; c < 32; ++c) {                           \
      float a = ws[OFF_M1B + c];                                               \
      _Pragma("unroll") for (int j = 0; j < 8; ++j)                            \
        a = fmaf(ws[OFF_M1 + 8*c + j], xi[j], a);                              \
      m1[c] = a;                                                               \
    }                                                                          \
    _Pragma("unroll") for (int c = 0; c < 32; ++c) {                           \
      float a = ws[OFF_M2B + c];                                               \
      _Pragma("unroll") for (int j = 0; j < 8; ++j)                            \
        a = fmaf(ws[OFF_M2 + 8*c + j], xi[j], a);                              \
      m2[c] = a;                                                               \
    }                                                                          \
    float sd[32];                                                              \
    _Pragma("unroll") for (int c = 0; c < 32; ++c) sd[c] = silu_f(d0[c]);      \
    _Pragma("unroll") for (int c = 0; c < 32; ++c) {                           \
      float a = m1[c] + d0[c];                                                 \
      _Pragma("unroll") for (int i = 0; i < 32; ++i)                           \
        a = fmaf(ws[OFF_W1S + 32*c + i], sd[i], a);                            \
      m1[c] = a;                                                               \
    }                                                                          \
    _Pragma("unroll") for (int c = 0; c < 32; ++c) sd[c] = silu_f(m1[c]);      \
    _Pragma("unroll") for (int c = 0; c < 32; ++c) {                           \
      float a = m2[c] + d0[c];                                                 \
      _Pragma("unroll") for (int i = 0; i < 32; ++i)                           \
        a = fmaf(ws[OFF_W2S + 32*c + i], sd[i], a);                            \
      SDL[c] = silu_f(a);                                                      \
    }                                                                          \
  }

__global__ __launch_bounds__(64, 1) void resnet_main(
    const float* __restrict__ P,  const float* __restrict__ DA,
    const float* __restrict__ QA, const float* __restrict__ VA,
    const float* __restrict__ ws,
    const float* __restrict__ Wtv, const float* __restrict__ btv,
    const float* __restrict__ Wv1, const float* __restrict__ bv1,
    const float* __restrict__ Wv2, const float* __restrict__ bv2,
    const float* __restrict__ Wvs, const float* __restrict__ bvs,
    float* __restrict__ out, int n_total)
{
    const int n = blockIdx.x * 64 + threadIdx.x;
    if (n >= n_total) return;
    const float* pn = P + n * 48;

    float out_acc = bvs[0];

    #pragma unroll 1
    for (int lq = 0; lq < 3; ++lq) {
        float qavg[32];
        #pragma unroll
        for (int c = 0; c < 32; ++c) qavg[c] = 0.f;

        #pragma unroll 1
        for (int var = 0; var < 4; ++var) {
            const float s_eta = (var >= 2) ? -1.f : 1.f;
            const float s_phi = (var == 1 || var == 2) ? -1.f : 1.f;

            float sdl0[32], sdl1[32];
            D_PART(0, sdl0)
            D_PART(1, sdl1)

            float q0[32], n1[32], n2[32];
            #pragma unroll
            for (int c = 0; c < 30; ++c) {
                float a = ws[OFF_QB + c];
                #pragma unroll
                for (int k = 0; k < 32; ++k) {
                    a = fmaf(ws[OFF_Q + 64*c + k],      sdl0[k], a);
                    a = fmaf(ws[OFF_Q + 64*c + 32 + k], sdl1[k], a);
                }
                q0[c] = a;
            }
            q0[30] = QA[n*6 + lq];
            q0[31] = QA[n*6 + 3 + lq];
            #pragma unroll
            for (int c = 0; c < 32; ++c) {
                float a = ws[OFF_N1B + c];
                #pragma unroll
                for (int k = 0; k < 32; ++k) {
                    a = fmaf(ws[OFF_N1 + 64*c + k],      sdl0[k], a);
                    a = fmaf(ws[OFF_N1 + 64*c + 32 + k], sdl1[k], a);
                }
                n1[c] = a;
            }
            #pragma unroll
            for (int c = 0; c < 32; ++c) {
                float a = ws[OFF_N2B + c];
                #pragma unroll
                for (int k = 0; k < 32; ++k) {
                    a = fmaf(ws[OFF_N2 + 64*c + k],      sdl0[k], a);
                    a = fmaf(ws[OFF_N2 + 64*c + 32 + k], sdl1[k], a);
                }
                n2[c] = a;
            }
            // sdl0/sdl1 dead from here
            float sq[32];
            #pragma unroll
            for (int c = 0; c < 32; ++c) sq[c] = silu_f(q0[c]);
            #pragma unroll
            for (int c = 0; c < 32; ++c) {
                float a = n1[c] + q0[c];
                #pragma unroll
                for (int i = 0; i < 32; ++i)
                    a = fmaf(ws[OFF_U1S + 32*c + i], sq[i], a);
                n1[c] = a;
            }
            #pragma unroll
            for (int c = 0; c < 32; ++c) sq[c] = silu_f(n1[c]);
            #pragma unroll
            for (int c = 0; c < 32; ++c) {
                float a = n2[c] + q0[c];
                #pragma unroll
                for (int i = 0; i < 32; ++i)
                    a = fmaf(ws[OFF_U2S + 32*c + i], sq[i], a);
                qavg[c] += silu_f(a);
            }
        } // var

        #pragma unroll
        for (int c = 0; c < 32; ++c) qavg[c] *= 0.25f;

        // head (tv/v1/v2/vs, all 1x1)
        const float va0 = VA[n*2], va1 = VA[n*2+1];
        float u0[64];
        #pragma unroll
        for (int c = 0; c < 64; ++c) {
            float a = fmaf(Wtv[34*c+32], va0, fmaf(Wtv[34*c+33], va1, btv[c]));
            #pragma unroll
            for (int i = 0; i < 32; ++i) a = fmaf(Wtv[34*c+i], qavg[i], a);
            u0[c] = a;
        }
        // qavg dead
        float su[64];
        #pragma unroll
        for (int c = 0; c < 64; ++c) su[c] = silu_f(u0[c]);
        float su2[64];
        #pragma unroll
        for (int c = 0; c < 64; ++c) {
            float a = bv1[c] + u0[c];
            #pragma unroll
            for (int i = 0; i < 64; ++i) a = fmaf(Wv1[64*c+i], su[i], a);
            su2[c] = silu_f(a);
        }
        #pragma unroll
        for (int c = 0; c < 64; ++c) {
            float a = bv2[c] + u0[c];
            #pragma unroll
            for (int i = 0; i < 64; ++i) a = fmaf(Wv2[64*c+i], su2[i], a);
            out_acc = fmaf(Wvs[3*c + lq], silu_f(a), out_acc);
        }
    } // lq

    out[n] = out_acc;
}

extern "C" void kernel_launch(void* const* d_in, const int* in_sizes, int n_in,
                              void* d_out, int out_size, void* d_ws, size_t ws_size,
                              hipStream_t stream)
{
    (void)n_in; (void)ws_size; (void)out_size;
    const float* P   = (const float*)d_in[1];
    const float* DA  = (const float*)d_in[2];
    const float* QA  = (const float*)d_in[3];
    const float* VA  = (const float*)d_in[4];
    const float* Wtd = (const float*)d_in[5];   const float* btd = (const float*)d_in[6];
    const float* Wdb = (const float*)d_in[7];   const float* bdb = (const float*)d_in[8];
    const float* Wdr1= (const float*)d_in[9];   const float* bdr1= (const float*)d_in[10];
    const float* Wdr2= (const float*)d_in[11];  const float* bdr2= (const float*)d_in[12];
    const float* Wtq = (const float*)d_in[13];  const float* btq = (const float*)d_in[14];
    const float* Wqb = (const float*)d_in[15];  const float* bqb = (const float*)d_in[16];
    const float* Wqr1= (const float*)d_in[17];  const float* bqr1= (const float*)d_in[18];
    const float* Wqr2= (const float*)d_in[19];  const float* bqr2= (const float*)d_in[20];
    const float* Wtv = (const float*)d_in[21];  const float* btv = (const float*)d_in[22];
    const float* Wv1 = (const float*)d_in[23];  const float* bv1 = (const float*)d_in[24];
    const float* Wv2 = (const float*)d_in[25];  const float* bv2 = (const float*)d_in[26];
    const float* Wvs = (const float*)d_in[27];  const float* bvs = (const float*)d_in[28];
    float* out = (float*)d_out;

    const int n_total = in_sizes[1] / 48;   // p is [N,4,12]

    precompute_ws<<<dim3(1), dim3(256), 0, stream>>>(
        Wtd, btd, Wdb, bdb, Wdr1, bdr1, Wdr2, bdr2,
        Wtq, btq, Wqb, bqb, Wqr1, bqr1, Wqr2, bqr2, (float*)d_ws);

    const int grid = (n_total + 63) / 64;
    resnet_main<<<dim3(grid), dim3(64), 0, stream>>>(
        P, DA, QA, VA, (const float*)d_ws,
        Wtv, btv, Wv1, bv1, Wv2, bv2, Wvs, bvs, out, n_total);
}

// Round 4
// 702.091 us; speedup vs baseline: 9.0562x; 6.0903x over previous
//
#include <hip/hip_runtime.h>

// MFMA rewrite: one wave = 16 samples, entire per-sample net as a chain of
// 16x16x32 fp16 MFMAs. Weights (all linear-linear compositions pre-folded)
// are pre-packed into A-fragment order by a precompute kernel into d_ws,
// staged to LDS per block. Activations live as C/D f32 fragments; between
// layers a D->B repack (fp16 pack + 8 __shfl) rearranges k across lane groups.
// Residuals ride the MFMA C operand; d0/q0 residuals are folded into weight
// rows; biases/da/qa/va enter via padded K-slots or targeted per-lane adds.

typedef _Float16 f16x8 __attribute__((ext_vector_type(8)));
typedef float f32x4 __attribute__((ext_vector_type(4)));

#define TILES 50
// tile map: L1=0..5, W1S=6..7, W2S=8..9, QN=10..21, U1S=22..23, U2S=24..25,
//           TV=26..33, V1=34..41, V2=42..49
// fbias map (floats): QBIAS=0..95, BV1=96..159, BV2=160..223, WVS=224..415
#define WS_TILE_DW (TILES*256)   // 12800 dwords of packed fp16 frags
#define WS_BIAS    12800         // then 416 f32
#define NBIAS      416

__device__ __forceinline__ float silu_f(float x){
    return x * __builtin_amdgcn_rcpf(1.0f + __expf(-x));
}
__device__ __forceinline__ f32x4 silu4(f32x4 v){
    f32x4 r; r.x=silu_f(v.x); r.y=silu_f(v.y); r.z=silu_f(v.z); r.w=silu_f(v.w);
    return r;
}
__device__ __forceinline__ unsigned pk(float a, float b){
    unsigned short lo = __builtin_bit_cast(unsigned short, (_Float16)a);
    unsigned short hi = __builtin_bit_cast(unsigned short, (_Float16)b);
    return ((unsigned)hi<<16) | (unsigned)lo;
}

// ---------------- precompute: composed weights -> A-frag order ----------------

__device__ float l1_Ad0(const float* Wdb, const float* Wtd, int c, int k){
    int h = k>>2, jr = k&3; float a = 0.f;
    for (int i=0;i<32;++i) a += Wdb[64*c+2*i+h]*Wtd[4*i+jr];
    return a;
}
__device__ float l1_AB(const float* Wdb,const float* bdb,const float* btd,int c){
    float b = bdb[c];
    for (int i=0;i<32;++i) b += (Wdb[64*c+2*i]+Wdb[64*c+2*i+1])*btd[i];
    return b;
}
__device__ float l1_M(const float* Wdr,const float* Wtd,int c,int k){
    int h=k>>2, jr=k&3; float a=0.f;
    for(int i=0;i<32;++i) a += Wdr[96*c+3*i+h]*Wtd[4*i+jr];
    return a;
}
__device__ float l1_MB(const float* Wdr,const float* bdr,const float* btd,int c){
    float b = bdr[c];
    for(int i=0;i<32;++i) b += (Wdr[96*c+3*i]+Wdr[96*c+3*i+1])*btd[i];
    return b;
}
__device__ float qn_Q(const float* Wqb, const float* Wtq, int c, int kg){
    int z=kg>>5, kk=kg&31; float a=0.f;
    for(int i=0;i<32;++i) a += Wqb[64*c+2*i+z]*Wtq[32*i+kk];
    return a;
}
__device__ float qn_N(const float* Wqr, const float* Wtq, int c, int kg){
    int z=kg>>5, kk=kg&31; float a=0.f;
    for(int i=0;i<32;++i) a += Wqr[96*c+3*i+z]*Wtq[32*i+kk];
    return a;
}

__global__ void precompute(
    const float* __restrict__ Wtd, const float* __restrict__ btd,
    const float* __restrict__ Wdb, const float* __restrict__ bdb,
    const float* __restrict__ Wdr1, const float* __restrict__ bdr1,
    const float* __restrict__ Wdr2, const float* __restrict__ bdr2,
    const float* __restrict__ Wtq, const float* __restrict__ btq,
    const float* __restrict__ Wqb, const float* __restrict__ bqb,
    const float* __restrict__ Wqr1, const float* __restrict__ bqr1,
    const float* __restrict__ Wqr2, const float* __restrict__ bqr2,
    const float* __restrict__ Wtv, const float* __restrict__ btv,
    const float* __restrict__ Wv1, const float* __restrict__ bv1,
    const float* __restrict__ Wv2, const float* __restrict__ bv2,
    const float* __restrict__ Wvs,
    float* __restrict__ wsf)
{
    const int tid = blockIdx.x*blockDim.x + threadIdx.x;
    const int stride = gridDim.x*blockDim.x;

    // fragment elements
    for (int it = tid; it < TILES*64; it += stride) {
        const int tile = it >> 6, lane = it & 63;
        const int m = lane & 15, g = lane >> 4;
        float v[8];
        #pragma unroll
        for (int j = 0; j < 8; ++j) {
            const int k = 8*g + j;
            float val = 0.f;
            if (tile < 6) {
                const int r = 16*tile + m;
                if (r < 32) {
                    if (r < 30) {
                        if (k < 8)      val = l1_Ad0(Wdb, Wtd, r, k);
                        else if (k==8)  val = l1_AB(Wdb, bdb, btd, r);
                    } else if (r == 30) val = (k==9)  ? 1.f : 0.f;
                    else                val = (k==10) ? 1.f : 0.f;
                } else {
                    const float* Wdr = (r<64)? Wdr1 : Wdr2;
                    const float* bdr = (r<64)? bdr1 : bdr2;
                    const int c = (r<64)? r-32 : r-64;
                    if (k < 8) {
                        val = l1_M(Wdr, Wtd, c, k);
                        if (c < 30) val += l1_Ad0(Wdb, Wtd, c, k);
                    } else if (k == 8) {
                        val = l1_MB(Wdr, bdr, btd, c);
                        if (c < 30) val += l1_AB(Wdb, bdb, btd, c);
                    } else if (k == 9)  val = (c==30)? 1.f : 0.f;
                    else if (k == 10)   val = (c==31)? 1.f : 0.f;
                }
            } else if (tile < 8)  { val = Wdr1[96*(16*(tile-6)+m) + 3*k + 2]; }
            else if (tile < 10)   { val = Wdr2[96*(16*(tile-8)+m) + 3*k + 2]; }
            else if (tile < 22) {
                const int tt = tile-10, r = 16*(tt>>1)+m, kg = 32*(tt&1)+k;
                if (r < 32) { if (r < 30) val = qn_Q(Wqb, Wtq, r, kg); }
                else {
                    const float* Wqr = (r<64)? Wqr1 : Wqr2;
                    const int c = (r<64)? r-32 : r-64;
                    val = qn_N(Wqr, Wtq, c, kg);
                    if (c < 30) val += qn_Q(Wqb, Wtq, c, kg);
                }
            }
            else if (tile < 24)  { val = Wqr1[96*(16*(tile-22)+m) + 3*k + 2]; }
            else if (tile < 26)  { val = Wqr2[96*(16*(tile-24)+m) + 3*k + 2]; }
            else if (tile < 34) {
                const int tt = tile-26, r = 16*(tt>>1)+m;
                if ((tt&1)==0) val = 0.25f*Wtv[34*r + k];   // qavg/4 folded
                else {
                    if (k==0) val = btv[r];
                    else if (k==1) val = Wtv[34*r+32];
                    else if (k==2) val = Wtv[34*r+33];
                }
            }
            else if (tile < 42) { const int tt=tile-34; val = Wv1[64*(16*(tt>>1)+m) + 32*(tt&1) + k]; }
            else                { const int tt=tile-42; val = Wv2[64*(16*(tt>>1)+m) + 32*(tt&1) + k]; }
            v[j] = val;
        }
        unsigned* wd = (unsigned*)wsf;
        const int base = tile*256 + lane*4;
        wd[base+0] = pk(v[0],v[1]);
        wd[base+1] = pk(v[2],v[3]);
        wd[base+2] = pk(v[4],v[5]);
        wd[base+3] = pk(v[6],v[7]);
    }

    // bias / wvs region (f32)
    for (int r = tid; r < NBIAS; r += stride) {
        float val = 0.f;
        if (r < 96) {
            if (r < 30) {
                float b = bqb[r];
                for (int i=0;i<32;++i) b += (Wqb[64*r+2*i]+Wqb[64*r+2*i+1])*btq[i];
                val = b;
            } else if (r >= 32) {
                const float* Wqr = (r<64)? Wqr1 : Wqr2;
                const float* bqr = (r<64)? bqr1 : bqr2;
                const int c = (r<64)? r-32 : r-64;
                float b = bqr[c];
                for (int i=0;i<32;++i) b += (Wqr[96*c+3*i]+Wqr[96*c+3*i+1])*btq[i];
                if (c < 30) {
                    float qb = bqb[c];
                    for (int i=0;i<32;++i) qb += (Wqb[64*c+2*i]+Wqb[64*c+2*i+1])*btq[i];
                    b += qb;
                }
                val = b;
            }
        }
        else if (r < 160) val = bv1[r-96];
        else if (r < 224) val = bv2[r-160];
        else { const int idx = r-224, lq = idx>>6, row = idx&63; val = Wvs[3*row + lq]; }
        wsf[WS_BIAS + r] = val;
    }
}

// ---------------- main kernel ----------------

__global__ __launch_bounds__(512, 4) void resnet_mfma(
    const float* __restrict__ P,  const float* __restrict__ DA,
    const float* __restrict__ QA, const float* __restrict__ VA,
    const float* __restrict__ wsf, const float* __restrict__ bvs,
    float* __restrict__ out, int n_total)
{
    __shared__ uint4 lw[TILES*64];
    __shared__ alignas(16) float fb[NBIAS];

    {
        const uint4* src = (const uint4*)wsf;
        uint4* fb4 = (uint4*)fb;
        for (int i = threadIdx.x; i < TILES*64 + NBIAS/4; i += blockDim.x) {
            if (i < TILES*64) lw[i] = src[i];
            else fb4[i - TILES*64] = src[i];
        }
    }
    __syncthreads();

    const int l  = threadIdx.x & 63;
    const int wv = threadIdx.x >> 6;
    const int c  = l & 15, g = l >> 4;
    const int s  = blockIdx.x*128 + wv*16 + c;
    const int sl = (s < n_total) ? s : (n_total-1);
    const bool g0 = (g==0), g1 = (g==1);

    const uint4* lwl = lw + l;
    #define LDA(T) __builtin_bit_cast(f16x8, lwl[(T)*64])
    #define MFMA(A,B,C) __builtin_amdgcn_mfma_f32_16x16x32_f16((A), __builtin_bit_cast(f16x8,(B)), (C), 0, 0, 0)

    // D->B repack: T0 = rows 4g..4g+3 (row block 0..15), T1 = rows 16..31
    const int srcA = ((l>>4)&1)*32 + (l&15);
    const int srcB = srcA + 16;
    const bool hiT = (l >= 32);
    #define REPACK(RES, T0, T1) {                                              \
        unsigned plo0 = pk((T0).x,(T0).y), phi0 = pk((T0).z,(T0).w);           \
        unsigned plo1 = pk((T1).x,(T1).y), phi1 = pk((T1).z,(T1).w);           \
        unsigned a0 = (unsigned)__shfl((int)plo0, srcA, 64);                   \
        unsigned a1 = (unsigned)__shfl((int)plo1, srcA, 64);                   \
        unsigned b0 = (unsigned)__shfl((int)phi0, srcA, 64);                   \
        unsigned b1 = (unsigned)__shfl((int)phi1, srcA, 64);                   \
        unsigned c0 = (unsigned)__shfl((int)plo0, srcB, 64);                   \
        unsigned c1 = (unsigned)__shfl((int)plo1, srcB, 64);                   \
        unsigned d0 = (unsigned)__shfl((int)phi0, srcB, 64);                   \
        unsigned d1 = (unsigned)__shfl((int)phi1, srcB, 64);                   \
        (RES).x = hiT?a1:a0; (RES).y = hiT?b1:b0;                              \
        (RES).z = hiT?c1:c0; (RES).w = hiT?d1:d0; }

    const float va0 = VA[2*sl], va1 = VA[2*sl+1];
    uint4 Bva; Bva.x=0; Bva.y=0; Bva.z=0; Bva.w=0;
    if (g0) { Bva.x = pk(1.0f, va0); Bva.y = pk(va1, 0.0f); }

    const unsigned me = g0 ? 0x80000000u : 0u;   // eta sign slots (hi of dw0, dw2)
    const unsigned mp = g0 ? 0x00008000u : 0u;   // phi sign slots (lo of dw1, dw3)

    const f32x4 z4 = {0.f,0.f,0.f,0.f};
    float out_acc = 0.0f;

    #pragma unroll 1
    for (int lq = 0; lq < 3; ++lq) {
        // base xi B-frags per ld tile (var=0 signs)
        uint4 xb[2];
        #pragma unroll
        for (int t = 0; t < 2; ++t) {
            const int pos = 4*lq + 2*t;
            float f0 = P[48*sl + pos],        f1 = P[48*sl + 12 + pos];
            float y0 = P[48*sl + 24 + pos] + 1.0f; y0 -= 2.0f*floorf(y0*0.5f);
            float f2 = y0 - 1.0f,             f3 = P[48*sl + 36 + pos];
            float f4 = P[48*sl + pos + 1],    f5 = P[48*sl + 12 + pos + 1];
            float y1 = P[48*sl + 24 + pos + 1] + 1.0f; y1 -= 2.0f*floorf(y1*0.5f);
            float f6 = y1 - 1.0f,             f7 = P[48*sl + 36 + pos + 1];
            float da0 = DA[12*sl + 2*lq + t];
            float da1 = DA[12*sl + 6 + 2*lq + t];
            uint4 xv; xv.x=0; xv.y=0; xv.z=0; xv.w=0;
            if (g0)      { xv.x = pk(f0,f1); xv.y = pk(f2,f3); xv.z = pk(f4,f5); xv.w = pk(f6,f7); }
            else if (g1) { xv.x = pk(1.0f, da0); xv.y = pk(da1, 0.0f); }
            xb[t] = xv;
        }
        const float qa30 = QA[6*sl + lq], qa31 = QA[6*sl + 3 + lq];
        const float qa30m = (g==3) ? qa30 : 0.0f;
        const float qa31m = (g==3) ? qa31 : 0.0f;

        f32x4 qav0 = z4, qav1 = z4;

        #pragma unroll 1
        for (int var = 0; var < 4; ++var) {
            const unsigned fe = (var>=2)? me : 0u;
            const unsigned fp = (var==1||var==2)? mp : 0u;
            uint4 Bxi[2];
            #pragma unroll
            for (int t=0;t<2;++t) {
                Bxi[t].x = xb[t].x ^ fe; Bxi[t].y = xb[t].y ^ fp;
                Bxi[t].z = xb[t].z ^ fe; Bxi[t].w = xb[t].w ^ fp;
            }

            // layer1: [96 x 32pad] -> d0,m1,m2 (m1/m2 carry +d0 residual + biases)
            f32x4 acc[6][2];
            #pragma unroll
            for (int mt=0; mt<6; ++mt)
                #pragma unroll
                for (int t=0;t<2;++t)
                    acc[mt][t] = MFMA(LDA(mt), Bxi[t], z4);

            // dr1: d1 = W1S*silu(d0) + (m1+d0)
            uint4 Bs[2];
            #pragma unroll
            for (int t=0;t<2;++t) { f32x4 s0=silu4(acc[0][t]), s1=silu4(acc[1][t]); REPACK(Bs[t], s0, s1); }
            #pragma unroll
            for (int t=0;t<2;++t) {
                acc[2][t] = MFMA(LDA(6), Bs[t], acc[2][t]);
                acc[3][t] = MFMA(LDA(7), Bs[t], acc[3][t]);
            }
            // dr2: d2 = W2S*silu(d1) + (m2+d0)
            #pragma unroll
            for (int t=0;t<2;++t) { f32x4 s0=silu4(acc[2][t]), s1=silu4(acc[3][t]); REPACK(Bs[t], s0, s1); }
            #pragma unroll
            for (int t=0;t<2;++t) {
                acc[4][t] = MFMA(LDA(8), Bs[t], acc[4][t]);
                acc[5][t] = MFMA(LDA(9), Bs[t], acc[5][t]);
            }
            // sdl = silu(d2) -> K-frags (t = ld = k-block)
            #pragma unroll
            for (int t=0;t<2;++t) { f32x4 s0=silu4(acc[4][t]), s1=silu4(acc[5][t]); REPACK(Bs[t], s0, s1); }

            // q-layer: [96 x 64] (q0; n1+q0; n2+q0 folds) + bias + qa inserts
            f32x4 q[6];
            #pragma unroll
            for (int mt=0; mt<6; ++mt) {
                q[mt] = MFMA(LDA(10+2*mt),   Bs[0], z4);
                q[mt] = MFMA(LDA(10+2*mt+1), Bs[1], q[mt]);
                q[mt] += *(const f32x4*)&fb[16*mt + 4*g];
            }
            q[1].z += qa30m; q[1].w += qa31m;
            q[3].z += qa30m; q[3].w += qa31m;
            q[5].z += qa30m; q[5].w += qa31m;

            uint4 Bq;
            { f32x4 s0=silu4(q[0]), s1=silu4(q[1]); REPACK(Bq, s0, s1); }
            q[2] = MFMA(LDA(22), Bq, q[2]);
            q[3] = MFMA(LDA(23), Bq, q[3]);
            { f32x4 s0=silu4(q[2]), s1=silu4(q[3]); REPACK(Bq, s0, s1); }
            q[4] = MFMA(LDA(24), Bq, q[4]);
            q[5] = MFMA(LDA(25), Bq, q[5]);
            qav0 += silu4(q[4]);
            qav1 += silu4(q[5]);
        } // var

        // head: tv (0.25 folded, bias+va via K-frag2) / v1 / v2 / vs
        uint4 BQ; REPACK(BQ, qav0, qav1);
        f32x4 u[4];
        #pragma unroll
        for (int mt=0; mt<4; ++mt) {
            u[mt] = MFMA(LDA(26+2*mt), BQ,  z4);
            u[mt] = MFMA(LDA(27+2*mt), Bva, u[mt]);
        }
        uint4 B0, B1;
        { f32x4 s0=silu4(u[0]), s1=silu4(u[1]); REPACK(B0, s0, s1); }
        { f32x4 s0=silu4(u[2]), s1=silu4(u[3]); REPACK(B1, s0, s1); }
        f32x4 w[4];
        #pragma unroll
        for (int mt=0; mt<4; ++mt) {
            w[mt] = MFMA(LDA(34+2*mt), B0, u[mt]);
            w[mt] = MFMA(LDA(35+2*mt), B1, w[mt]);
            w[mt] += *(const f32x4*)&fb[96 + 16*mt + 4*g];
        }
        { f32x4 s0=silu4(w[0]), s1=silu4(w[1]); REPACK(B0, s0, s1); }
        { f32x4 s0=silu4(w[2]), s1=silu4(w[3]); REPACK(B1, s0, s1); }
        #pragma unroll
        for (int mt=0; mt<4; ++mt) {
            w[mt] = MFMA(LDA(42+2*mt), B0, u[mt]);
            w[mt] = MFMA(LDA(43+2*mt), B1, w[mt]);
            w[mt] += *(const f32x4*)&fb[160 + 16*mt + 4*g];
        }
        #pragma unroll
        for (int mt=0; mt<4; ++mt) {
            const f32x4 wvs = *(const f32x4*)&fb[224 + 64*lq + 16*mt + 4*g];
            out_acc += wvs.x*silu_f(w[mt].x) + wvs.y*silu_f(w[mt].y)
                     + wvs.z*silu_f(w[mt].z) + wvs.w*silu_f(w[mt].w);
        }
    } // lq

    out_acc += __shfl_xor(out_acc, 16, 64);
    out_acc += __shfl_xor(out_acc, 32, 64);
    if (g == 0 && s < n_total) out[s] = out_acc + bvs[0];
}

extern "C" void kernel_launch(void* const* d_in, const int* in_sizes, int n_in,
                              void* d_out, int out_size, void* d_ws, size_t ws_size,
                              hipStream_t stream)
{
    (void)n_in; (void)ws_size; (void)out_size;
    const float* P   = (const float*)d_in[1];
    const float* DA  = (const float*)d_in[2];
    const float* QA  = (const float*)d_in[3];
    const float* VA  = (const float*)d_in[4];
    const float* Wtd = (const float*)d_in[5];   const float* btd = (const float*)d_in[6];
    const float* Wdb = (const float*)d_in[7];   const float* bdb = (const float*)d_in[8];
    const float* Wdr1= (const float*)d_in[9];   const float* bdr1= (const float*)d_in[10];
    const float* Wdr2= (const float*)d_in[11];  const float* bdr2= (const float*)d_in[12];
    const float* Wtq = (const float*)d_in[13];  const float* btq = (const float*)d_in[14];
    const float* Wqb = (const float*)d_in[15];  const float* bqb = (const float*)d_in[16];
    const float* Wqr1= (const float*)d_in[17];  const float* bqr1= (const float*)d_in[18];
    const float* Wqr2= (const float*)d_in[19];  const float* bqr2= (const float*)d_in[20];
    const float* Wtv = (const float*)d_in[21];  const float* btv = (const float*)d_in[22];
    const float* Wv1 = (const float*)d_in[23];  const float* bv1 = (const float*)d_in[24];
    const float* Wv2 = (const float*)d_in[25];  const float* bv2 = (const float*)d_in[26];
    const float* Wvs = (const float*)d_in[27];  const float* bvs = (const float*)d_in[28];
    float* out = (float*)d_out;

    const int n_total = in_sizes[1] / 48;   // p is [N,4,12]

    precompute<<<dim3(8), dim3(512), 0, stream>>>(
        Wtd, btd, Wdb, bdb, Wdr1, bdr1, Wdr2, bdr2,
        Wtq, btq, Wqb, bqb, Wqr1, bqr1, Wqr2, bqr2,
        Wtv, btv, Wv1, bv1, Wv2, bv2, Wvs, (float*)d_ws);

    const int grid = (n_total + 127) / 128;   // 512 threads = 8 waves x 16 samples
    resnet_mfma<<<dim3(grid), dim3(512), 0, stream>>>(
        P, DA, QA, VA, (const float*)d_ws, bvs, out, n_total);
}

// Round 5
// 353.338 us; speedup vs baseline: 17.9948x; 1.9870x over previous
//
#include <hip/hip_runtime.h>

// MFMA rewrite: one wave = 16 samples, entire per-sample net as a chain of
// 16x16x32 fp16 MFMAs. Weights (all linear-linear compositions pre-folded)
// are pre-packed into A-fragment order by a precompute kernel into d_ws,
// staged to LDS per block. Activations live as C/D f32 fragments; between
// layers a D->B repack (fp16 pack + 8 __shfl) rearranges k across lane groups.
// Residuals ride the MFMA C operand; d0/q0 residuals are folded into weight
// rows; biases/da/qa/va enter via padded K-slots or targeted per-lane adds.
//
// Round 5: __launch_bounds__(512, 2). Empirical hipcc rule: VGPR cap ~=
// 256/min_waves_per_EU. Round 4's (512,4) capped at 64 VGPR -> ~2GB of
// scratch spill traffic (FETCH 1.5GB, WRITE 0.5GB). Liveness is ~100 floats,
// so a 128 cap fits spill-free at 16 waves/CU.

typedef _Float16 f16x8 __attribute__((ext_vector_type(8)));
typedef float f32x4 __attribute__((ext_vector_type(4)));

#define TILES 50
// tile map: L1=0..5, W1S=6..7, W2S=8..9, QN=10..21, U1S=22..23, U2S=24..25,
//           TV=26..33, V1=34..41, V2=42..49
// fbias map (floats): QBIAS=0..95, BV1=96..159, BV2=160..223, WVS=224..415
#define WS_TILE_DW (TILES*256)   // 12800 dwords of packed fp16 frags
#define WS_BIAS    12800         // then 416 f32
#define NBIAS      416

__device__ __forceinline__ float silu_f(float x){
    return x * __builtin_amdgcn_rcpf(1.0f + __expf(-x));
}
__device__ __forceinline__ f32x4 silu4(f32x4 v){
    f32x4 r; r.x=silu_f(v.x); r.y=silu_f(v.y); r.z=silu_f(v.z); r.w=silu_f(v.w);
    return r;
}
__device__ __forceinline__ unsigned pk(float a, float b){
    unsigned short lo = __builtin_bit_cast(unsigned short, (_Float16)a);
    unsigned short hi = __builtin_bit_cast(unsigned short, (_Float16)b);
    return ((unsigned)hi<<16) | (unsigned)lo;
}

// ---------------- precompute: composed weights -> A-frag order ----------------

__device__ float l1_Ad0(const float* Wdb, const float* Wtd, int c, int k){
    int h = k>>2, jr = k&3; float a = 0.f;
    for (int i=0;i<32;++i) a += Wdb[64*c+2*i+h]*Wtd[4*i+jr];
    return a;
}
__device__ float l1_AB(const float* Wdb,const float* bdb,const float* btd,int c){
    float b = bdb[c];
    for (int i=0;i<32;++i) b += (Wdb[64*c+2*i]+Wdb[64*c+2*i+1])*btd[i];
    return b;
}
__device__ float l1_M(const float* Wdr,const float* Wtd,int c,int k){
    int h=k>>2, jr=k&3; float a=0.f;
    for(int i=0;i<32;++i) a += Wdr[96*c+3*i+h]*Wtd[4*i+jr];
    return a;
}
__device__ float l1_MB(const float* Wdr,const float* bdr,const float* btd,int c){
    float b = bdr[c];
    for(int i=0;i<32;++i) b += (Wdr[96*c+3*i]+Wdr[96*c+3*i+1])*btd[i];
    return b;
}
__device__ float qn_Q(const float* Wqb, const float* Wtq, int c, int kg){
    int z=kg>>5, kk=kg&31; float a=0.f;
    for(int i=0;i<32;++i) a += Wqb[64*c+2*i+z]*Wtq[32*i+kk];
    return a;
}
__device__ float qn_N(const float* Wqr, const float* Wtq, int c, int kg){
    int z=kg>>5, kk=kg&31; float a=0.f;
    for(int i=0;i<32;++i) a += Wqr[96*c+3*i+z]*Wtq[32*i+kk];
    return a;
}

__global__ void precompute(
    const float* __restrict__ Wtd, const float* __restrict__ btd,
    const float* __restrict__ Wdb, const float* __restrict__ bdb,
    const float* __restrict__ Wdr1, const float* __restrict__ bdr1,
    const float* __restrict__ Wdr2, const float* __restrict__ bdr2,
    const float* __restrict__ Wtq, const float* __restrict__ btq,
    const float* __restrict__ Wqb, const float* __restrict__ bqb,
    const float* __restrict__ Wqr1, const float* __restrict__ bqr1,
    const float* __restrict__ Wqr2, const float* __restrict__ bqr2,
    const float* __restrict__ Wtv, const float* __restrict__ btv,
    const float* __restrict__ Wv1, const float* __restrict__ bv1,
    const float* __restrict__ Wv2, const float* __restrict__ bv2,
    const float* __restrict__ Wvs,
    float* __restrict__ wsf)
{
    const int tid = blockIdx.x*blockDim.x + threadIdx.x;
    const int stride = gridDim.x*blockDim.x;

    // fragment elements
    for (int it = tid; it < TILES*64; it += stride) {
        const int tile = it >> 6, lane = it & 63;
        const int m = lane & 15, g = lane >> 4;
        float v[8];
        #pragma unroll
        for (int j = 0; j < 8; ++j) {
            const int k = 8*g + j;
            float val = 0.f;
            if (tile < 6) {
                const int r = 16*tile + m;
                if (r < 32) {
                    if (r < 30) {
                        if (k < 8)      val = l1_Ad0(Wdb, Wtd, r, k);
                        else if (k==8)  val = l1_AB(Wdb, bdb, btd, r);
                    } else if (r == 30) val = (k==9)  ? 1.f : 0.f;
                    else                val = (k==10) ? 1.f : 0.f;
                } else {
                    const float* Wdr = (r<64)? Wdr1 : Wdr2;
                    const float* bdr = (r<64)? bdr1 : bdr2;
                    const int c = (r<64)? r-32 : r-64;
                    if (k < 8) {
                        val = l1_M(Wdr, Wtd, c, k);
                        if (c < 30) val += l1_Ad0(Wdb, Wtd, c, k);
                    } else if (k == 8) {
                        val = l1_MB(Wdr, bdr, btd, c);
                        if (c < 30) val += l1_AB(Wdb, bdb, btd, c);
                    } else if (k == 9)  val = (c==30)? 1.f : 0.f;
                    else if (k == 10)   val = (c==31)? 1.f : 0.f;
                }
            } else if (tile < 8)  { val = Wdr1[96*(16*(tile-6)+m) + 3*k + 2]; }
            else if (tile < 10)   { val = Wdr2[96*(16*(tile-8)+m) + 3*k + 2]; }
            else if (tile < 22) {
                const int tt = tile-10, r = 16*(tt>>1)+m, kg = 32*(tt&1)+k;
                if (r < 32) { if (r < 30) val = qn_Q(Wqb, Wtq, r, kg); }
                else {
                    const float* Wqr = (r<64)? Wqr1 : Wqr2;
                    const int c = (r<64)? r-32 : r-64;
                    val = qn_N(Wqr, Wtq, c, kg);
                    if (c < 30) val += qn_Q(Wqb, Wtq, c, kg);
                }
            }
            else if (tile < 24)  { val = Wqr1[96*(16*(tile-22)+m) + 3*k + 2]; }
            else if (tile < 26)  { val = Wqr2[96*(16*(tile-24)+m) + 3*k + 2]; }
            else if (tile < 34) {
                const int tt = tile-26, r = 16*(tt>>1)+m;
                if ((tt&1)==0) val = 0.25f*Wtv[34*r + k];   // qavg/4 folded
                else {
                    if (k==0) val = btv[r];
                    else if (k==1) val = Wtv[34*r+32];
                    else if (k==2) val = Wtv[34*r+33];
                }
            }
            else if (tile < 42) { const int tt=tile-34; val = Wv1[64*(16*(tt>>1)+m) + 32*(tt&1) + k]; }
            else                { const int tt=tile-42; val = Wv2[64*(16*(tt>>1)+m) + 32*(tt&1) + k]; }
            v[j] = val;
        }
        unsigned* wd = (unsigned*)wsf;
        const int base = tile*256 + lane*4;
        wd[base+0] = pk(v[0],v[1]);
        wd[base+1] = pk(v[2],v[3]);
        wd[base+2] = pk(v[4],v[5]);
        wd[base+3] = pk(v[6],v[7]);
    }

    // bias / wvs region (f32)
    for (int r = tid; r < NBIAS; r += stride) {
        float val = 0.f;
        if (r < 96) {
            if (r < 30) {
                float b = bqb[r];
                for (int i=0;i<32;++i) b += (Wqb[64*r+2*i]+Wqb[64*r+2*i+1])*btq[i];
                val = b;
            } else if (r >= 32) {
                const float* Wqr = (r<64)? Wqr1 : Wqr2;
                const float* bqr = (r<64)? bqr1 : bqr2;
                const int c = (r<64)? r-32 : r-64;
                float b = bqr[c];
                for (int i=0;i<32;++i) b += (Wqr[96*c+3*i]+Wqr[96*c+3*i+1])*btq[i];
                if (c < 30) {
                    float qb = bqb[c];
                    for (int i=0;i<32;++i) qb += (Wqb[64*c+2*i]+Wqb[64*c+2*i+1])*btq[i];
                    b += qb;
                }
                val = b;
            }
        }
        else if (r < 160) val = bv1[r-96];
        else if (r < 224) val = bv2[r-160];
        else { const int idx = r-224, lq = idx>>6, row = idx&63; val = Wvs[3*row + lq]; }
        wsf[WS_BIAS + r] = val;
    }
}

// ---------------- main kernel ----------------

__global__ __launch_bounds__(512, 2) void resnet_mfma(
    const float* __restrict__ P,  const float* __restrict__ DA,
    const float* __restrict__ QA, const float* __restrict__ VA,
    const float* __restrict__ wsf, const float* __restrict__ bvs,
    float* __restrict__ out, int n_total)
{
    __shared__ uint4 lw[TILES*64];
    __shared__ alignas(16) float fb[NBIAS];

    {
        const uint4* src = (const uint4*)wsf;
        uint4* fb4 = (uint4*)fb;
        for (int i = threadIdx.x; i < TILES*64 + NBIAS/4; i += blockDim.x) {
            if (i < TILES*64) lw[i] = src[i];
            else fb4[i - TILES*64] = src[i];
        }
    }
    __syncthreads();

    const int l  = threadIdx.x & 63;
    const int wv = threadIdx.x >> 6;
    const int c  = l & 15, g = l >> 4;
    const int s  = blockIdx.x*128 + wv*16 + c;
    const int sl = (s < n_total) ? s : (n_total-1);
    const bool g0 = (g==0), g1 = (g==1);

    const uint4* lwl = lw + l;
    #define LDA(T) __builtin_bit_cast(f16x8, lwl[(T)*64])
    #define MFMA(A,B,C) __builtin_amdgcn_mfma_f32_16x16x32_f16((A), __builtin_bit_cast(f16x8,(B)), (C), 0, 0, 0)

    // D->B repack: T0 = rows 4g..4g+3 (row block 0..15), T1 = rows 16..31
    const int srcA = ((l>>4)&1)*32 + (l&15);
    const int srcB = srcA + 16;
    const bool hiT = (l >= 32);
    #define REPACK(RES, T0, T1) {                                              \
        unsigned plo0 = pk((T0).x,(T0).y), phi0 = pk((T0).z,(T0).w);           \
        unsigned plo1 = pk((T1).x,(T1).y), phi1 = pk((T1).z,(T1).w);           \
        unsigned a0 = (unsigned)__shfl((int)plo0, srcA, 64);                   \
        unsigned a1 = (unsigned)__shfl((int)plo1, srcA, 64);                   \
        unsigned b0 = (unsigned)__shfl((int)phi0, srcA, 64);                   \
        unsigned b1 = (unsigned)__shfl((int)phi1, srcA, 64);                   \
        unsigned c0 = (unsigned)__shfl((int)plo0, srcB, 64);                   \
        unsigned c1 = (unsigned)__shfl((int)plo1, srcB, 64);                   \
        unsigned d0 = (unsigned)__shfl((int)phi0, srcB, 64);                   \
        unsigned d1 = (unsigned)__shfl((int)phi1, srcB, 64);                   \
        (RES).x = hiT?a1:a0; (RES).y = hiT?b1:b0;                              \
        (RES).z = hiT?c1:c0; (RES).w = hiT?d1:d0; }

    const float va0 = VA[2*sl], va1 = VA[2*sl+1];
    uint4 Bva; Bva.x=0; Bva.y=0; Bva.z=0; Bva.w=0;
    if (g0) { Bva.x = pk(1.0f, va0); Bva.y = pk(va1, 0.0f); }

    const unsigned me = g0 ? 0x80000000u : 0u;   // eta sign slots (hi of dw0, dw2)
    const unsigned mp = g0 ? 0x00008000u : 0u;   // phi sign slots (lo of dw1, dw3)

    const f32x4 z4 = {0.f,0.f,0.f,0.f};
    float out_acc = 0.0f;

    #pragma unroll 1
    for (int lq = 0; lq < 3; ++lq) {
        // base xi B-frags per ld tile (var=0 signs)
        uint4 xb[2];
        #pragma unroll
        for (int t = 0; t < 2; ++t) {
            const int pos = 4*lq + 2*t;
            float f0 = P[48*sl + pos],        f1 = P[48*sl + 12 + pos];
            float y0 = P[48*sl + 24 + pos] + 1.0f; y0 -= 2.0f*floorf(y0*0.5f);
            float f2 = y0 - 1.0f,             f3 = P[48*sl + 36 + pos];
            float f4 = P[48*sl + pos + 1],    f5 = P[48*sl + 12 + pos + 1];
            float y1 = P[48*sl + 24 + pos + 1] + 1.0f; y1 -= 2.0f*floorf(y1*0.5f);
            float f6 = y1 - 1.0f,             f7 = P[48*sl + 36 + pos + 1];
            float da0 = DA[12*sl + 2*lq + t];
            float da1 = DA[12*sl + 6 + 2*lq + t];
            uint4 xv; xv.x=0; xv.y=0; xv.z=0; xv.w=0;
            if (g0)      { xv.x = pk(f0,f1); xv.y = pk(f2,f3); xv.z = pk(f4,f5); xv.w = pk(f6,f7); }
            else if (g1) { xv.x = pk(1.0f, da0); xv.y = pk(da1, 0.0f); }
            xb[t] = xv;
        }
        const float qa30 = QA[6*sl + lq], qa31 = QA[6*sl + 3 + lq];
        const float qa30m = (g==3) ? qa30 : 0.0f;
        const float qa31m = (g==3) ? qa31 : 0.0f;

        f32x4 qav0 = z4, qav1 = z4;

        #pragma unroll 1
        for (int var = 0; var < 4; ++var) {
            const unsigned fe = (var>=2)? me : 0u;
            const unsigned fp = (var==1||var==2)? mp : 0u;
            uint4 Bxi[2];
            #pragma unroll
            for (int t=0;t<2;++t) {
                Bxi[t].x = xb[t].x ^ fe; Bxi[t].y = xb[t].y ^ fp;
                Bxi[t].z = xb[t].z ^ fe; Bxi[t].w = xb[t].w ^ fp;
            }

            // layer1: [96 x 32pad] -> d0,m1,m2 (m1/m2 carry +d0 residual + biases)
            f32x4 acc[6][2];
            #pragma unroll
            for (int mt=0; mt<6; ++mt)
                #pragma unroll
                for (int t=0;t<2;++t)
                    acc[mt][t] = MFMA(LDA(mt), Bxi[t], z4);

            // dr1: d1 = W1S*silu(d0) + (m1+d0)
            uint4 Bs[2];
            #pragma unroll
            for (int t=0;t<2;++t) { f32x4 s0=silu4(acc[0][t]), s1=silu4(acc[1][t]); REPACK(Bs[t], s0, s1); }
            #pragma unroll
            for (int t=0;t<2;++t) {
                acc[2][t] = MFMA(LDA(6), Bs[t], acc[2][t]);
                acc[3][t] = MFMA(LDA(7), Bs[t], acc[3][t]);
            }
            // dr2: d2 = W2S*silu(d1) + (m2+d0)
            #pragma unroll
            for (int t=0;t<2;++t) { f32x4 s0=silu4(acc[2][t]), s1=silu4(acc[3][t]); REPACK(Bs[t], s0, s1); }
            #pragma unroll
            for (int t=0;t<2;++t) {
                acc[4][t] = MFMA(LDA(8), Bs[t], acc[4][t]);
                acc[5][t] = MFMA(LDA(9), Bs[t], acc[5][t]);
            }
            // sdl = silu(d2) -> K-frags (t = ld = k-block)
            #pragma unroll
            for (int t=0;t<2;++t) { f32x4 s0=silu4(acc[4][t]), s1=silu4(acc[5][t]); REPACK(Bs[t], s0, s1); }

            // q-layer: [96 x 64] (q0; n1+q0; n2+q0 folds) + bias + qa inserts
            f32x4 q[6];
            #pragma unroll
            for (int mt=0; mt<6; ++mt) {
                q[mt] = MFMA(LDA(10+2*mt),   Bs[0], z4);
                q[mt] = MFMA(LDA(10+2*mt+1), Bs[1], q[mt]);
                q[mt] += *(const f32x4*)&fb[16*mt + 4*g];
            }
            q[1].z += qa30m; q[1].w += qa31m;
            q[3].z += qa30m; q[3].w += qa31m;
            q[5].z += qa30m; q[5].w += qa31m;

            uint4 Bq;
            { f32x4 s0=silu4(q[0]), s1=silu4(q[1]); REPACK(Bq, s0, s1); }
            q[2] = MFMA(LDA(22), Bq, q[2]);
            q[3] = MFMA(LDA(23), Bq, q[3]);
            { f32x4 s0=silu4(q[2]), s1=silu4(q[3]); REPACK(Bq, s0, s1); }
            q[4] = MFMA(LDA(24), Bq, q[4]);
            q[5] = MFMA(LDA(25), Bq, q[5]);
            qav0 += silu4(q[4]);
            qav1 += silu4(q[5]);
        } // var

        // head: tv (0.25 folded, bias+va via K-frag2) / v1 / v2 / vs
        uint4 BQ; REPACK(BQ, qav0, qav1);
        f32x4 u[4];
        #pragma unroll
        for (int mt=0; mt<4; ++mt) {
            u[mt] = MFMA(LDA(26+2*mt), BQ,  z4);
            u[mt] = MFMA(LDA(27+2*mt), Bva, u[mt]);
        }
        uint4 B0, B1;
        { f32x4 s0=silu4(u[0]), s1=silu4(u[1]); REPACK(B0, s0, s1); }
        { f32x4 s0=silu4(u[2]), s1=silu4(u[3]); REPACK(B1, s0, s1); }
        f32x4 w[4];
        #pragma unroll
        for (int mt=0; mt<4; ++mt) {
            w[mt] = MFMA(LDA(34+2*mt), B0, u[mt]);
            w[mt] = MFMA(LDA(35+2*mt), B1, w[mt]);
            w[mt] += *(const f32x4*)&fb[96 + 16*mt + 4*g];
        }
        { f32x4 s0=silu4(w[0]), s1=silu4(w[1]); REPACK(B0, s0, s1); }
        { f32x4 s0=silu4(w[2]), s1=silu4(w[3]); REPACK(B1, s0, s1); }
        #pragma unroll
        for (int mt=0; mt<4; ++mt) {
            w[mt] = MFMA(LDA(42+2*mt), B0, u[mt]);
            w[mt] = MFMA(LDA(43+2*mt), B1, w[mt]);
            w[mt] += *(const f32x4*)&fb[160 + 16*mt + 4*g];
        }
        #pragma unroll
        for (int mt=0; mt<4; ++mt) {
            const f32x4 wvs = *(const f32x4*)&fb[224 + 64*lq + 16*mt + 4*g];
            out_acc += wvs.x*silu_f(w[mt].x) + wvs.y*silu_f(w[mt].y)
                     + wvs.z*silu_f(w[mt].z) + wvs.w*silu_f(w[mt].w);
        }
    } // lq

    out_acc += __shfl_xor(out_acc, 16, 64);
    out_acc += __shfl_xor(out_acc, 32, 64);
    if (g == 0 && s < n_total) out[s] = out_acc + bvs[0];
}

extern "C" void kernel_launch(void* const* d_in, const int* in_sizes, int n_in,
                              void* d_out, int out_size, void* d_ws, size_t ws_size,
                              hipStream_t stream)
{
    (void)n_in; (void)ws_size; (void)out_size;
    const float* P   = (const float*)d_in[1];
    const float* DA  = (const float*)d_in[2];
    const float* QA  = (const float*)d_in[3];
    const float* VA  = (const float*)d_in[4];
    const float* Wtd = (const float*)d_in[5];   const float* btd = (const float*)d_in[6];
    const float* Wdb = (const float*)d_in[7];   const float* bdb = (const float*)d_in[8];
    const float* Wdr1= (const float*)d_in[9];   const float* bdr1= (const float*)d_in[10];
    const float* Wdr2= (const float*)d_in[11];  const float* bdr2= (const float*)d_in[12];
    const float* Wtq = (const float*)d_in[13];  const float* btq = (const float*)d_in[14];
    const float* Wqb = (const float*)d_in[15];  const float* bqb = (const float*)d_in[16];
    const float* Wqr1= (const float*)d_in[17];  const float* bqr1= (const float*)d_in[18];
    const float* Wqr2= (const float*)d_in[19];  const float* bqr2= (const float*)d_in[20];
    const float* Wtv = (const float*)d_in[21];  const float* btv = (const float*)d_in[22];
    const float* Wv1 = (const float*)d_in[23];  const float* bv1 = (const float*)d_in[24];
    const float* Wv2 = (const float*)d_in[25];  const float* bv2 = (const float*)d_in[26];
    const float* Wvs = (const float*)d_in[27];  const float* bvs = (const float*)d_in[28];
    float* out = (float*)d_out;

    const int n_total = in_sizes[1] / 48;   // p is [N,4,12]

    precompute<<<dim3(8), dim3(512), 0, stream>>>(
        Wtd, btd, Wdb, bdb, Wdr1, bdr1, Wdr2, bdr2,
        Wtq, btq, Wqb, bqb, Wqr1, bqr1, Wqr2, bqr2,
        Wtv, btv, Wv1, bv1, Wv2, bv2, Wvs, (float*)d_ws);

    const int grid = (n_total + 127) / 128;   // 512 threads = 8 waves x 16 samples
    resnet_mfma<<<dim3(grid), dim3(512), 0, stream>>>(
        P, DA, QA, VA, (const float*)d_ws, bvs, out, n_total);
}

// Round 6
// 336.290 us; speedup vs baseline: 18.9071x; 1.0507x over previous
//
#include <hip/hip_runtime.h>

// MFMA version: one wave = 16 samples, whole net as a chain of 16x16x32 fp16
// MFMAs, weights pre-composed + pre-packed to A-frag order in d_ws and staged
// to LDS. Round 6: (a) __launch_bounds__(512,1) -> 256 VGPR cap (empirical
// hipcc rule: cap = 256/min_waves_arg; 128 was ~30 regs short -> 180MB spill
// stores). (b) d-chain runs t=0 then t=1 SERIALLY: peak layer1 liveness drops
// 48->24+8 regs. Target: zero scratch traffic, VALU-bound ~100-190us.

typedef _Float16 f16x8 __attribute__((ext_vector_type(8)));
typedef float f32x4 __attribute__((ext_vector_type(4)));

#define TILES 50
// tile map: L1=0..5, W1S=6..7, W2S=8..9, QN=10..21, U1S=22..23, U2S=24..25,
//           TV=26..33, V1=34..41, V2=42..49
// fbias map (floats): QBIAS=0..95, BV1=96..159, BV2=160..223, WVS=224..415
#define WS_TILE_DW (TILES*256)
#define WS_BIAS    12800
#define NBIAS      416

__device__ __forceinline__ float silu_f(float x){
    return x * __builtin_amdgcn_rcpf(1.0f + __expf(-x));
}
__device__ __forceinline__ f32x4 silu4(f32x4 v){
    f32x4 r; r.x=silu_f(v.x); r.y=silu_f(v.y); r.z=silu_f(v.z); r.w=silu_f(v.w);
    return r;
}
__device__ __forceinline__ unsigned pk(float a, float b){
    unsigned short lo = __builtin_bit_cast(unsigned short, (_Float16)a);
    unsigned short hi = __builtin_bit_cast(unsigned short, (_Float16)b);
    return ((unsigned)hi<<16) | (unsigned)lo;
}

// ---------------- precompute: composed weights -> A-frag order ----------------

__device__ float l1_Ad0(const float* Wdb, const float* Wtd, int c, int k){
    int h = k>>2, jr = k&3; float a = 0.f;
    for (int i=0;i<32;++i) a += Wdb[64*c+2*i+h]*Wtd[4*i+jr];
    return a;
}
__device__ float l1_AB(const float* Wdb,const float* bdb,const float* btd,int c){
    float b = bdb[c];
    for (int i=0;i<32;++i) b += (Wdb[64*c+2*i]+Wdb[64*c+2*i+1])*btd[i];
    return b;
}
__device__ float l1_M(const float* Wdr,const float* Wtd,int c,int k){
    int h=k>>2, jr=k&3; float a=0.f;
    for(int i=0;i<32;++i) a += Wdr[96*c+3*i+h]*Wtd[4*i+jr];
    return a;
}
__device__ float l1_MB(const float* Wdr,const float* bdr,const float* btd,int c){
    float b = bdr[c];
    for(int i=0;i<32;++i) b += (Wdr[96*c+3*i]+Wdr[96*c+3*i+1])*btd[i];
    return b;
}
__device__ float qn_Q(const float* Wqb, const float* Wtq, int c, int kg){
    int z=kg>>5, kk=kg&31; float a=0.f;
    for(int i=0;i<32;++i) a += Wqb[64*c+2*i+z]*Wtq[32*i+kk];
    return a;
}
__device__ float qn_N(const float* Wqr, const float* Wtq, int c, int kg){
    int z=kg>>5, kk=kg&31; float a=0.f;
    for(int i=0;i<32;++i) a += Wqr[96*c+3*i+z]*Wtq[32*i+kk];
    return a;
}

__global__ void precompute(
    const float* __restrict__ Wtd, const float* __restrict__ btd,
    const float* __restrict__ Wdb, const float* __restrict__ bdb,
    const float* __restrict__ Wdr1, const float* __restrict__ bdr1,
    const float* __restrict__ Wdr2, const float* __restrict__ bdr2,
    const float* __restrict__ Wtq, const float* __restrict__ btq,
    const float* __restrict__ Wqb, const float* __restrict__ bqb,
    const float* __restrict__ Wqr1, const float* __restrict__ bqr1,
    const float* __restrict__ Wqr2, const float* __restrict__ bqr2,
    const float* __restrict__ Wtv, const float* __restrict__ btv,
    const float* __restrict__ Wv1, const float* __restrict__ bv1,
    const float* __restrict__ Wv2, const float* __restrict__ bv2,
    const float* __restrict__ Wvs,
    float* __restrict__ wsf)
{
    const int tid = blockIdx.x*blockDim.x + threadIdx.x;
    const int stride = gridDim.x*blockDim.x;

    for (int it = tid; it < TILES*64; it += stride) {
        const int tile = it >> 6, lane = it & 63;
        const int m = lane & 15, g = lane >> 4;
        float v[8];
        #pragma unroll
        for (int j = 0; j < 8; ++j) {
            const int k = 8*g + j;
            float val = 0.f;
            if (tile < 6) {
                const int r = 16*tile + m;
                if (r < 32) {
                    if (r < 30) {
                        if (k < 8)      val = l1_Ad0(Wdb, Wtd, r, k);
                        else if (k==8)  val = l1_AB(Wdb, bdb, btd, r);
                    } else if (r == 30) val = (k==9)  ? 1.f : 0.f;
                    else                val = (k==10) ? 1.f : 0.f;
                } else {
                    const float* Wdr = (r<64)? Wdr1 : Wdr2;
                    const float* bdr = (r<64)? bdr1 : bdr2;
                    const int c = (r<64)? r-32 : r-64;
                    if (k < 8) {
                        val = l1_M(Wdr, Wtd, c, k);
                        if (c < 30) val += l1_Ad0(Wdb, Wtd, c, k);
                    } else if (k == 8) {
                        val = l1_MB(Wdr, bdr, btd, c);
                        if (c < 30) val += l1_AB(Wdb, bdb, btd, c);
                    } else if (k == 9)  val = (c==30)? 1.f : 0.f;
                    else if (k == 10)   val = (c==31)? 1.f : 0.f;
                }
            } else if (tile < 8)  { val = Wdr1[96*(16*(tile-6)+m) + 3*k + 2]; }
            else if (tile < 10)   { val = Wdr2[96*(16*(tile-8)+m) + 3*k + 2]; }
            else if (tile < 22) {
                const int tt = tile-10, r = 16*(tt>>1)+m, kg = 32*(tt&1)+k;
                if (r < 32) { if (r < 30) val = qn_Q(Wqb, Wtq, r, kg); }
                else {
                    const float* Wqr = (r<64)? Wqr1 : Wqr2;
                    const int c = (r<64)? r-32 : r-64;
                    val = qn_N(Wqr, Wtq, c, kg);
                    if (c < 30) val += qn_Q(Wqb, Wtq, c, kg);
                }
            }
            else if (tile < 24)  { val = Wqr1[96*(16*(tile-22)+m) + 3*k + 2]; }
            else if (tile < 26)  { val = Wqr2[96*(16*(tile-24)+m) + 3*k + 2]; }
            else if (tile < 34) {
                const int tt = tile-26, r = 16*(tt>>1)+m;
                if ((tt&1)==0) val = 0.25f*Wtv[34*r + k];
                else {
                    if (k==0) val = btv[r];
                    else if (k==1) val = Wtv[34*r+32];
                    else if (k==2) val = Wtv[34*r+33];
                }
            }
            else if (tile < 42) { const int tt=tile-34; val = Wv1[64*(16*(tt>>1)+m) + 32*(tt&1) + k]; }
            else                { const int tt=tile-42; val = Wv2[64*(16*(tt>>1)+m) + 32*(tt&1) + k]; }
            v[j] = val;
        }
        unsigned* wd = (unsigned*)wsf;
        const int base = tile*256 + lane*4;
        wd[base+0] = pk(v[0],v[1]);
        wd[base+1] = pk(v[2],v[3]);
        wd[base+2] = pk(v[4],v[5]);
        wd[base+3] = pk(v[6],v[7]);
    }

    for (int r = tid; r < NBIAS; r += stride) {
        float val = 0.f;
        if (r < 96) {
            if (r < 30) {
                float b = bqb[r];
                for (int i=0;i<32;++i) b += (Wqb[64*r+2*i]+Wqb[64*r+2*i+1])*btq[i];
                val = b;
            } else if (r >= 32) {
                const float* Wqr = (r<64)? Wqr1 : Wqr2;
                const float* bqr = (r<64)? bqr1 : bqr2;
                const int c = (r<64)? r-32 : r-64;
                float b = bqr[c];
                for (int i=0;i<32;++i) b += (Wqr[96*c+3*i]+Wqr[96*c+3*i+1])*btq[i];
                if (c < 30) {
                    float qb = bqb[c];
                    for (int i=0;i<32;++i) qb += (Wqb[64*c+2*i]+Wqb[64*c+2*i+1])*btq[i];
                    b += qb;
                }
                val = b;
            }
        }
        else if (r < 160) val = bv1[r-96];
        else if (r < 224) val = bv2[r-160];
        else { const int idx = r-224, lq = idx>>6, row = idx&63; val = Wvs[3*row + lq]; }
        wsf[WS_BIAS + r] = val;
    }
}

// ---------------- main kernel ----------------

__global__ __launch_bounds__(512, 1) void resnet_mfma(
    const float* __restrict__ P,  const float* __restrict__ DA,
    const float* __restrict__ QA, const float* __restrict__ VA,
    const float* __restrict__ wsf, const float* __restrict__ bvs,
    float* __restrict__ out, int n_total)
{
    __shared__ uint4 lw[TILES*64];
    __shared__ alignas(16) float fb[NBIAS];

    {
        const uint4* src = (const uint4*)wsf;
        uint4* fb4 = (uint4*)fb;
        for (int i = threadIdx.x; i < TILES*64 + NBIAS/4; i += blockDim.x) {
            if (i < TILES*64) lw[i] = src[i];
            else fb4[i - TILES*64] = src[i];
        }
    }
    __syncthreads();

    const int l  = threadIdx.x & 63;
    const int wv = threadIdx.x >> 6;
    const int c  = l & 15, g = l >> 4;
    const int s  = blockIdx.x*128 + wv*16 + c;
    const int sl = (s < n_total) ? s : (n_total-1);
    const bool g0 = (g==0), g1 = (g==1);

    const uint4* lwl = lw + l;
    #define LDA(T) __builtin_bit_cast(f16x8, lwl[(T)*64])
    #define MFMA(A,B,C) __builtin_amdgcn_mfma_f32_16x16x32_f16((A), __builtin_bit_cast(f16x8,(B)), (C), 0, 0, 0)

    const int srcA = ((l>>4)&1)*32 + (l&15);
    const int srcB = srcA + 16;
    const bool hiT = (l >= 32);
    #define REPACK(RES, T0, T1) {                                              \
        unsigned plo0 = pk((T0).x,(T0).y), phi0 = pk((T0).z,(T0).w);           \
        unsigned plo1 = pk((T1).x,(T1).y), phi1 = pk((T1).z,(T1).w);           \
        unsigned a0 = (unsigned)__shfl((int)plo0, srcA, 64);                   \
        unsigned a1 = (unsigned)__shfl((int)plo1, srcA, 64);                   \
        unsigned b0 = (unsigned)__shfl((int)phi0, srcA, 64);                   \
        unsigned b1 = (unsigned)__shfl((int)phi1, srcA, 64);                   \
        unsigned c0 = (unsigned)__shfl((int)plo0, srcB, 64);                   \
        unsigned c1 = (unsigned)__shfl((int)plo1, srcB, 64);                   \
        unsigned d0 = (unsigned)__shfl((int)phi0, srcB, 64);                   \
        unsigned d1 = (unsigned)__shfl((int)phi1, srcB, 64);                   \
        (RES).x = hiT?a1:a0; (RES).y = hiT?b1:b0;                              \
        (RES).z = hiT?c1:c0; (RES).w = hiT?d1:d0; }

    const float va0 = VA[2*sl], va1 = VA[2*sl+1];
    uint4 Bva; Bva.x=0; Bva.y=0; Bva.z=0; Bva.w=0;
    if (g0) { Bva.x = pk(1.0f, va0); Bva.y = pk(va1, 0.0f); }

    const unsigned me = g0 ? 0x80000000u : 0u;
    const unsigned mp = g0 ? 0x00008000u : 0u;

    const f32x4 z4 = {0.f,0.f,0.f,0.f};
    float out_acc = 0.0f;

    #pragma unroll 1
    for (int lq = 0; lq < 3; ++lq) {
        uint4 xb[2];
        #pragma unroll
        for (int t = 0; t < 2; ++t) {
            const int pos = 4*lq + 2*t;
            float f0 = P[48*sl + pos],        f1 = P[48*sl + 12 + pos];
            float y0 = P[48*sl + 24 + pos] + 1.0f; y0 -= 2.0f*floorf(y0*0.5f);
            float f2 = y0 - 1.0f,             f3 = P[48*sl + 36 + pos];
            float f4 = P[48*sl + pos + 1],    f5 = P[48*sl + 12 + pos + 1];
            float y1 = P[48*sl + 24 + pos + 1] + 1.0f; y1 -= 2.0f*floorf(y1*0.5f);
            float f6 = y1 - 1.0f,             f7 = P[48*sl + 36 + pos + 1];
            float da0 = DA[12*sl + 2*lq + t];
            float da1 = DA[12*sl + 6 + 2*lq + t];
            uint4 xv; xv.x=0; xv.y=0; xv.z=0; xv.w=0;
            if (g0)      { xv.x = pk(f0,f1); xv.y = pk(f2,f3); xv.z = pk(f4,f5); xv.w = pk(f6,f7); }
            else if (g1) { xv.x = pk(1.0f, da0); xv.y = pk(da1, 0.0f); }
            xb[t] = xv;
        }
        const float qa30 = QA[6*sl + lq], qa31 = QA[6*sl + 3 + lq];
        const float qa30m = (g==3) ? qa30 : 0.0f;
        const float qa31m = (g==3) ? qa31 : 0.0f;

        f32x4 qav0 = z4, qav1 = z4;

        #pragma unroll 1
        for (int var = 0; var < 4; ++var) {
            const unsigned fe = (var>=2)? me : 0u;
            const unsigned fp = (var==1||var==2)? mp : 0u;

            // ---- d-chain, t = 0 then 1 SERIALLY (halves layer1 liveness) ----
            uint4 Bs[2];
            #pragma unroll
            for (int t = 0; t < 2; ++t) {
                uint4 Bxi;
                Bxi.x = xb[t].x ^ fe; Bxi.y = xb[t].y ^ fp;
                Bxi.z = xb[t].z ^ fe; Bxi.w = xb[t].w ^ fp;

                f32x4 a0 = MFMA(LDA(0), Bxi, z4);
                f32x4 a1 = MFMA(LDA(1), Bxi, z4);
                f32x4 a2 = MFMA(LDA(2), Bxi, z4);
                f32x4 a3 = MFMA(LDA(3), Bxi, z4);
                f32x4 a4 = MFMA(LDA(4), Bxi, z4);
                f32x4 a5 = MFMA(LDA(5), Bxi, z4);

                uint4 Bt;
                { f32x4 s0=silu4(a0), s1=silu4(a1); REPACK(Bt, s0, s1); }
                a2 = MFMA(LDA(6), Bt, a2);
                a3 = MFMA(LDA(7), Bt, a3);
                { f32x4 s0=silu4(a2), s1=silu4(a3); REPACK(Bt, s0, s1); }
                a4 = MFMA(LDA(8), Bt, a4);
                a5 = MFMA(LDA(9), Bt, a5);
                { f32x4 s0=silu4(a4), s1=silu4(a5); REPACK(Bs[t], s0, s1); }
            }

            // ---- q-layer: [96 x 64] + bias + qa inserts ----
            f32x4 q[6];
            #pragma unroll
            for (int mt=0; mt<6; ++mt) {
                q[mt] = MFMA(LDA(10+2*mt),   Bs[0], z4);
                q[mt] = MFMA(LDA(10+2*mt+1), Bs[1], q[mt]);
                q[mt] += *(const f32x4*)&fb[16*mt + 4*g];
            }
            q[1].z += qa30m; q[1].w += qa31m;
            q[3].z += qa30m; q[3].w += qa31m;
            q[5].z += qa30m; q[5].w += qa31m;

            uint4 Bq;
            { f32x4 s0=silu4(q[0]), s1=silu4(q[1]); REPACK(Bq, s0, s1); }
            q[2] = MFMA(LDA(22), Bq, q[2]);
            q[3] = MFMA(LDA(23), Bq, q[3]);
            { f32x4 s0=silu4(q[2]), s1=silu4(q[3]); REPACK(Bq, s0, s1); }
            q[4] = MFMA(LDA(24), Bq, q[4]);
            q[5] = MFMA(LDA(25), Bq, q[5]);
            qav0 += silu4(q[4]);
            qav1 += silu4(q[5]);
        } // var

        // ---- head ----
        uint4 BQ; REPACK(BQ, qav0, qav1);
        f32x4 u[4];
        #pragma unroll
        for (int mt=0; mt<4; ++mt) {
            u[mt] = MFMA(LDA(26+2*mt), BQ,  z4);
            u[mt] = MFMA(LDA(27+2*mt), Bva, u[mt]);
        }
        uint4 B0, B1;
        { f32x4 s0=silu4(u[0]), s1=silu4(u[1]); REPACK(B0, s0, s1); }
        { f32x4 s0=silu4(u[2]), s1=silu4(u[3]); REPACK(B1, s0, s1); }
        f32x4 w[4];
        #pragma unroll
        for (int mt=0; mt<4; ++mt) {
            w[mt] = MFMA(LDA(34+2*mt), B0, u[mt]);
            w[mt] = MFMA(LDA(35+2*mt), B1, w[mt]);
            w[mt] += *(const f32x4*)&fb[96 + 16*mt + 4*g];
        }
        { f32x4 s0=silu4(w[0]), s1=silu4(w[1]); REPACK(B0, s0, s1); }
        { f32x4 s0=silu4(w[2]), s1=silu4(w[3]); REPACK(B1, s0, s1); }
        #pragma unroll
        for (int mt=0; mt<4; ++mt) {
            w[mt] = MFMA(LDA(42+2*mt), B0, u[mt]);
            w[mt] = MFMA(LDA(43+2*mt), B1, w[mt]);
            w[mt] += *(const f32x4*)&fb[160 + 16*mt + 4*g];
        }
        #pragma unroll
        for (int mt=0; mt<4; ++mt) {
            const f32x4 wvs = *(const f32x4*)&fb[224 + 64*lq + 16*mt + 4*g];
            out_acc += wvs.x*silu_f(w[mt].x) + wvs.y*silu_f(w[mt].y)
                     + wvs.z*silu_f(w[mt].z) + wvs.w*silu_f(w[mt].w);
        }
    } // lq

    out_acc += __shfl_xor(out_acc, 16, 64);
    out_acc += __shfl_xor(out_acc, 32, 64);
    if (g == 0 && s < n_total) out[s] = out_acc + bvs[0];
}

extern "C" void kernel_launch(void* const* d_in, const int* in_sizes, int n_in,
                              void* d_out, int out_size, void* d_ws, size_t ws_size,
                              hipStream_t stream)
{
    (void)n_in; (void)ws_size; (void)out_size;
    const float* P   = (const float*)d_in[1];
    const float* DA  = (const float*)d_in[2];
    const float* QA  = (const float*)d_in[3];
    const float* VA  = (const float*)d_in[4];
    const float* Wtd = (const float*)d_in[5];   const float* btd = (const float*)d_in[6];
    const float* Wdb = (const float*)d_in[7];   const float* bdb = (const float*)d_in[8];
    const float* Wdr1= (const float*)d_in[9];   const float* bdr1= (const float*)d_in[10];
    const float* Wdr2= (const float*)d_in[11];  const float* bdr2= (const float*)d_in[12];
    const float* Wtq = (const float*)d_in[13];  const float* btq = (const float*)d_in[14];
    const float* Wqb = (const float*)d_in[15];  const float* bqb = (const float*)d_in[16];
    const float* Wqr1= (const float*)d_in[17];  const float* bqr1= (const float*)d_in[18];
    const float* Wqr2= (const float*)d_in[19];  const float* bqr2= (const float*)d_in[20];
    const float* Wtv = (const float*)d_in[21];  const float* btv = (const float*)d_in[22];
    const float* Wv1 = (const float*)d_in[23];  const float* bv1 = (const float*)d_in[24];
    const float* Wv2 = (const float*)d_in[25];  const float* bv2 = (const float*)d_in[26];
    const float* Wvs = (const float*)d_in[27];  const float* bvs = (const float*)d_in[28];
    float* out = (float*)d_out;

    const int n_total = in_sizes[1] / 48;   // p is [N,4,12]

    precompute<<<dim3(8), dim3(512), 0, stream>>>(
        Wtd, btd, Wdb, bdb, Wdr1, bdr1, Wdr2, bdr2,
        Wtq, btq, Wqb, bqb, Wqr1, bqr1, Wqr2, bqr2,
        Wtv, btv, Wv1, bv1, Wv2, bv2, Wvs, (float*)d_ws);

    const int grid = (n_total + 127) / 128;   // 512 threads = 8 waves x 16 samples
    resnet_mfma<<<dim3(grid), dim3(512), 0, stream>>>(
        P, DA, QA, VA, (const float*)d_ws, bvs, out, n_total);
}